// Round 3
// baseline (1265.268 us; speedup 1.0000x reference)
//
#include <hip/hip_runtime.h>
#include <hip/hip_bf16.h>
#include <hip/hip_fp16.h>

// MusicGNN — 3-layer GCN encoder + MLP link predictor.
// N=100000, F_IN=128, HID=64, OUT=32, E=3.2M edges, EL=1M label edges.
// Inputs: float32 (x, weights, biases), int32 (edge indices).
// Output float32: [link_pred (1M) | z (100000*32)] concatenated flat.
//
// R14: gemm_scale<128,64> was latency-bound (74us, VGPR=248, LDS=66.5KB,
// occupancy 9.8% = 2 waves/SIMD, VALUBusy 19%). Fix: __launch_bounds__
// min-waves=4 caps VGPR at 128 (no spill: body needs ~100), and x is
// staged in K=64 halves so xs LDS drops 33.8->17.4KB (layer-1 total
// 66.5->49.4KB => 3 blocks/CU; K=64 layers 33.4KB => 4 blocks/CU).
// gemm_uv gets the same VGPR cap. decode_edge: 4x4B uv loads -> 2x8B.
// Sort pipeline (R13 chist/colscan) unchanged.

#define BINA_CHUNK 4096

// ---------------- per-chunk bucket histogram ----------------

__global__ __launch_bounds__(512) void bhist_kernel(const int* __restrict__ colv,
                                                    int* __restrict__ chist,
                                                    int E, int nbuk) {
    __shared__ int hist[800];
    int base = blockIdx.x * BINA_CHUNK;
    int end = min(base + BINA_CHUNK, E);
    for (int i = threadIdx.x; i < nbuk; i += 512) hist[i] = 0;
    __syncthreads();
    int e = base + threadIdx.x * 4;
    for (; e + 4 <= end; e += 2048) {
        int4 c4 = *(const int4*)&colv[e];
        atomicAdd(&hist[c4.x >> 7], 1);
        atomicAdd(&hist[c4.y >> 7], 1);
        atomicAdd(&hist[c4.z >> 7], 1);
        atomicAdd(&hist[c4.w >> 7], 1);
    }
    for (; e < end; ++e) atomicAdd(&hist[colv[e] >> 7], 1);
    __syncthreads();
    for (int b = threadIdx.x; b < nbuk; b += 512)
        chist[(size_t)blockIdx.x * nbuk + b] = hist[b];
}

// ---------------- column scan: chist[c][b] -> exclusive prefix over c ----------------

__global__ __launch_bounds__(256) void colscan_kernel(int* __restrict__ chist,
                                                      int* __restrict__ bcount,
                                                      int nchunk, int nbuk) {
    __shared__ int sh[256];
    const int b = blockIdx.x;
    const int c0 = threadIdx.x * 4;
    int v[4]; int s = 0;
#pragma unroll
    for (int i = 0; i < 4; ++i) {
        int c = c0 + i;
        v[i] = (c < nchunk) ? chist[(size_t)c * nbuk + b] : 0;
        s += v[i];
    }
    sh[threadIdx.x] = s;
    __syncthreads();
#pragma unroll
    for (int off = 1; off < 256; off <<= 1) {
        int y = (threadIdx.x >= (unsigned)off) ? sh[threadIdx.x - off] : 0;
        __syncthreads();
        sh[threadIdx.x] += y;
        __syncthreads();
    }
    int ex = sh[threadIdx.x] - s;
#pragma unroll
    for (int i = 0; i < 4; ++i) {
        int c = c0 + i;
        if (c < nchunk) { chist[(size_t)c * nbuk + b] = ex; ex += v[i]; }
    }
    if (threadIdx.x == 255) bcount[b] = sh[255];
}

// ---------------- bucket scan ----------------

__global__ __launch_bounds__(256) void bscan_kernel(const int* __restrict__ bcount,
                                                    int* __restrict__ bbase,
                                                    int nbuk, int* __restrict__ offsets, int N) {
    __shared__ int sh[256];
    int base = threadIdx.x * 4;
    int v[4]; int tsum = 0;
#pragma unroll
    for (int i = 0; i < 4; ++i) { int idx = base + i; v[i] = (idx < nbuk) ? bcount[idx] : 0; tsum += v[i]; }
    sh[threadIdx.x] = tsum;
    __syncthreads();
#pragma unroll
    for (int off = 1; off < 256; off <<= 1) {
        int y = (threadIdx.x >= (unsigned)off) ? sh[threadIdx.x - off] : 0;
        __syncthreads();
        sh[threadIdx.x] += y;
        __syncthreads();
    }
    int ex = sh[threadIdx.x] - tsum;
#pragma unroll
    for (int i = 0; i < 4; ++i) {
        int idx = base + i;
        if (idx < nbuk) { bbase[idx] = ex; ex += v[i]; }
        else if (idx == nbuk) { bbase[idx] = ex; offsets[N] = ex; }  // = E
    }
}

// ---------------- Phase A: scatter into buckets (deterministic chunk bases) ----------------

__global__ __launch_bounds__(512) void binA_kernel(const int* __restrict__ rowv,
                                                   const int* __restrict__ colv,
                                                   const int* __restrict__ chist,
                                                   const int* __restrict__ bbase,
                                                   int* __restrict__ pairs,
                                                   int E, int nbuk) {
    __shared__ int pos[800];
    int base = blockIdx.x * BINA_CHUNK;
    int end = min(base + BINA_CHUNK, E);
    for (int b = threadIdx.x; b < nbuk; b += 512)
        pos[b] = bbase[b] + chist[(size_t)blockIdx.x * nbuk + b];
    __syncthreads();
    int e = base + threadIdx.x * 4;
    for (; e + 4 <= end; e += 2048) {
        int4 c4 = *(const int4*)&colv[e];
        int4 r4 = *(const int4*)&rowv[e];
        int g0 = atomicAdd(&pos[c4.x >> 7], 1); pairs[g0] = (r4.x << 7) | (c4.x & 127);
        int g1 = atomicAdd(&pos[c4.y >> 7], 1); pairs[g1] = (r4.y << 7) | (c4.y & 127);
        int g2 = atomicAdd(&pos[c4.z >> 7], 1); pairs[g2] = (r4.z << 7) | (c4.z & 127);
        int g3 = atomicAdd(&pos[c4.w >> 7], 1); pairs[g3] = (r4.w << 7) | (c4.w & 127);
    }
    for (; e < end; ++e) {
        int c = colv[e];
        int g = atomicAdd(&pos[c >> 7], 1);
        pairs[g] = (rowv[e] << 7) | (c & 127);
    }
}

// ---------------- Phase B: per bucket — node hist, scan, offsets+dinv, scatter ----------------

__global__ __launch_bounds__(512) void binB_kernel(const int* __restrict__ pairs,
                                                   const int* __restrict__ bbase,
                                                   int* __restrict__ offsets,
                                                   float* __restrict__ dinv,
                                                   int* __restrict__ edge_src, int N) {
    __shared__ int lcnt[128];
    __shared__ int sc[128];
    __shared__ int lcur[128];
    int nodeBeg = blockIdx.x << 7;
    int segBeg = bbase[blockIdx.x];
    int segEnd = bbase[blockIdx.x + 1];
    if (threadIdx.x < 128) lcnt[threadIdx.x] = 0;
    __syncthreads();
    for (int e = segBeg + threadIdx.x; e < segEnd; e += 512)
        atomicAdd(&lcnt[pairs[e] & 127], 1);
    __syncthreads();
    int v = (threadIdx.x < 128) ? lcnt[threadIdx.x] : 0;
    if (threadIdx.x < 128) sc[threadIdx.x] = v;
    __syncthreads();
    for (int off = 1; off < 128; off <<= 1) {
        int y = 0;
        if (threadIdx.x < 128 && threadIdx.x >= (unsigned)off) y = sc[threadIdx.x - off];
        __syncthreads();
        if (threadIdx.x < 128) sc[threadIdx.x] += y;
        __syncthreads();
    }
    if (threadIdx.x < 128) {
        int ex = sc[threadIdx.x] - v;
        lcur[threadIdx.x] = ex;
        int node = nodeBeg + threadIdx.x;
        if (node < N) {
            offsets[node] = segBeg + ex;
            dinv[node] = rsqrtf((float)(v + 1));
        }
    }
    __syncthreads();
    for (int e = segBeg + threadIdx.x; e < segEnd; e += 512) {
        int p = pairs[e];
        int rel = atomicAdd(&lcur[p & 127], 1);
        edge_src[segBeg + rel] = p >> 7;
    }
}

// ---------------- GEMM + dinv scale, fp16 out (K-halved xs staging, VGPR-capped) ----------------

template <int K, int NOUT>
__global__ __launch_bounds__(16 * (NOUT / 4), 4) void gemm_scale(const float* __restrict__ in_,
                                                                 const float* __restrict__ W,
                                                                 const float* __restrict__ dinv,
                                                                 __half* __restrict__ out, int N) {
    constexpr int TPB = 16 * (NOUT / 4);
    constexpr int KS = (K > 64) ? 64 : K;     // xs stage depth
    constexpr int XPITCH = KS + 4;
    __shared__ float xs[64 * XPITCH];
    __shared__ float ws[K * NOUT];

    const int tid = threadIdx.x;
    const int nodeBase = blockIdx.x * 64;

    for (int i = tid; i < K * NOUT / 4; i += TPB)
        *(float4*)&ws[i * 4] = *(const float4*)&W[i * 4];

    const int jg = tid % (NOUT / 4);
    const int ng = tid / (NOUT / 4);

    float acc[4][4];
#pragma unroll
    for (int i = 0; i < 4; ++i)
#pragma unroll
        for (int j = 0; j < 4; ++j) acc[i][j] = 0.f;

    for (int kh = 0; kh < K / KS; ++kh) {
        if (kh) __syncthreads();   // previous compute done before xs overwrite
        for (int i = tid; i < 64 * KS / 4; i += TPB) {
            int row = i / (KS / 4), c = i % (KS / 4);
            int src = nodeBase + row; if (src >= N) src = N - 1;
            *(float4*)&xs[row * XPITCH + c * 4] =
                *(const float4*)&in_[(size_t)src * K + kh * KS + c * 4];
        }
        __syncthreads();

        for (int kc = 0; kc < KS / 4; ++kc) {
            float4 xv[4], wv[4];
#pragma unroll
            for (int ni = 0; ni < 4; ++ni)
                xv[ni] = *(const float4*)&xs[(ng * 4 + ni) * XPITCH + kc * 4];
#pragma unroll
            for (int t = 0; t < 4; ++t)
                wv[t] = *(const float4*)&ws[(kh * KS + kc * 4 + t) * NOUT + jg * 4];
#pragma unroll
            for (int ni = 0; ni < 4; ++ni) {
                acc[ni][0] = fmaf(xv[ni].x, wv[0].x, acc[ni][0]);
                acc[ni][1] = fmaf(xv[ni].x, wv[0].y, acc[ni][1]);
                acc[ni][2] = fmaf(xv[ni].x, wv[0].z, acc[ni][2]);
                acc[ni][3] = fmaf(xv[ni].x, wv[0].w, acc[ni][3]);
                acc[ni][0] = fmaf(xv[ni].y, wv[1].x, acc[ni][0]);
                acc[ni][1] = fmaf(xv[ni].y, wv[1].y, acc[ni][1]);
                acc[ni][2] = fmaf(xv[ni].y, wv[1].z, acc[ni][2]);
                acc[ni][3] = fmaf(xv[ni].y, wv[1].w, acc[ni][3]);
                acc[ni][0] = fmaf(xv[ni].z, wv[2].x, acc[ni][0]);
                acc[ni][1] = fmaf(xv[ni].z, wv[2].y, acc[ni][1]);
                acc[ni][2] = fmaf(xv[ni].z, wv[2].z, acc[ni][2]);
                acc[ni][3] = fmaf(xv[ni].z, wv[2].w, acc[ni][3]);
                acc[ni][0] = fmaf(xv[ni].w, wv[3].x, acc[ni][0]);
                acc[ni][1] = fmaf(xv[ni].w, wv[3].y, acc[ni][1]);
                acc[ni][2] = fmaf(xv[ni].w, wv[3].z, acc[ni][2]);
                acc[ni][3] = fmaf(xv[ni].w, wv[3].w, acc[ni][3]);
            }
        }
    }

#pragma unroll
    for (int ni = 0; ni < 4; ++ni) {
        int node = nodeBase + ng * 4 + ni;
        if (node < N) {
            float dn = dinv[node];
            __half2* op = (__half2*)(out + (size_t)node * NOUT + jg * 4);
            op[0] = __floats2half2_rn(acc[ni][0] * dn, acc[ni][1] * dn);
            op[1] = __floats2half2_rn(acc[ni][2] * dn, acc[ni][3] * dn);
        }
    }
}

// ---------------- Pull aggregation: packed half2 gathers, fp32 accumulate ----------------

template <int F, bool RELU>
__global__ __launch_bounds__(256) void agg_pull(const __half* __restrict__ h,
                                                const float* __restrict__ dinv,
                                                const float* __restrict__ bias,
                                                const int* __restrict__ edge_src,
                                                const int* __restrict__ offsets,
                                                float* __restrict__ out, int N) {
    constexpr int LPN = F / 2;        // lanes per node
    constexpr int GPW = 64 / LPN;     // nodes per wave
    int lane = threadIdx.x & 63;
    int wave = (blockIdx.x * 256 + (int)threadIdx.x) >> 6;
    int g = lane / LPN;
    int fl = lane % LPN;              // feature-pair index
    int node = wave * GPW + g;
    if (node >= N) return;
    float dn = dinv[node];
    int beg = offsets[node], end = offsets[node + 1];
    const __half2* __restrict__ hp = (const __half2*)h;

    float2 sv = __half22float2(hp[(size_t)node * LPN + fl]);  // self-loop
    float a0x = sv.x, a0y = sv.y;
    float a1x = 0.f, a1y = 0.f, a2x = 0.f, a2y = 0.f, a3x = 0.f, a3y = 0.f;

    int j = beg;
    for (; j + 8 <= end; j += 8) {
        int s0 = edge_src[j],     s1 = edge_src[j + 1], s2 = edge_src[j + 2], s3 = edge_src[j + 3];
        int s4 = edge_src[j + 4], s5 = edge_src[j + 5], s6 = edge_src[j + 6], s7 = edge_src[j + 7];
        __half2 v0 = hp[(size_t)s0 * LPN + fl];
        __half2 v1 = hp[(size_t)s1 * LPN + fl];
        __half2 v2 = hp[(size_t)s2 * LPN + fl];
        __half2 v3 = hp[(size_t)s3 * LPN + fl];
        __half2 v4 = hp[(size_t)s4 * LPN + fl];
        __half2 v5 = hp[(size_t)s5 * LPN + fl];
        __half2 v6 = hp[(size_t)s6 * LPN + fl];
        __half2 v7 = hp[(size_t)s7 * LPN + fl];
        float2 f0 = __half22float2(v0), f1 = __half22float2(v1);
        float2 f2 = __half22float2(v2), f3 = __half22float2(v3);
        float2 f4 = __half22float2(v4), f5 = __half22float2(v5);
        float2 f6 = __half22float2(v6), f7 = __half22float2(v7);
        a0x += f0.x; a0y += f0.y; a1x += f1.x; a1y += f1.y;
        a2x += f2.x; a2y += f2.y; a3x += f3.x; a3y += f3.y;
        a0x += f4.x; a0y += f4.y; a1x += f5.x; a1y += f5.y;
        a2x += f6.x; a2y += f6.y; a3x += f7.x; a3y += f7.y;
    }
    for (; j + 2 <= end; j += 2) {
        int s0 = edge_src[j], s1 = edge_src[j + 1];
        float2 f0 = __half22float2(hp[(size_t)s0 * LPN + fl]);
        float2 f1 = __half22float2(hp[(size_t)s1 * LPN + fl]);
        a0x += f0.x; a0y += f0.y; a1x += f1.x; a1y += f1.y;
    }
    if (j < end) {
        float2 f0 = __half22float2(hp[(size_t)edge_src[j] * LPN + fl]);
        a0x += f0.x; a0y += f0.y;
    }

    float2 bv = *(const float2*)&bias[fl * 2];
    float rx = ((a0x + a1x) + (a2x + a3x)) * dn + bv.x;
    float ry = ((a0y + a1y) + (a2y + a3y)) * dn + bv.y;
    if (RELU) { rx = fmaxf(rx, 0.f); ry = fmaxf(ry, 0.f); }
    *(float2*)&out[(size_t)node * F + fl * 2] = make_float2(rx, ry);
}

// ---------------- Decode stage 1: uv[n] = [z@W1_top | z@W1_bot] (fp16 out) ----------------

__global__ __launch_bounds__(256, 4) void gemm_uv(const float* __restrict__ z,   // [N,32]
                                                  const float* __restrict__ W1,  // [64,64]
                                                  __half* __restrict__ uv, int N) {
    constexpr int ZPITCH = 36;
    __shared__ float zs[64 * ZPITCH];
    __shared__ float ws[64 * 64];
    const int tid = threadIdx.x;
    const int nodeBase = blockIdx.x * 64;

    for (int i = tid; i < 64 * 64 / 4; i += 256)
        *(float4*)&ws[i * 4] = *(const float4*)&W1[i * 4];
    for (int i = tid; i < 64 * 8; i += 256) {
        int row = i / 8, c = i % 8;
        int src = nodeBase + row; if (src >= N) src = N - 1;
        *(float4*)&zs[row * ZPITCH + c * 4] = *(const float4*)&z[(size_t)src * 32 + c * 4];
    }
    __syncthreads();

    const int jg = tid % 16;
    const int ng = tid / 16;

    float au[4][4], av[4][4];
#pragma unroll
    for (int i = 0; i < 4; ++i)
#pragma unroll
        for (int j = 0; j < 4; ++j) { au[i][j] = 0.f; av[i][j] = 0.f; }

    for (int kc = 0; kc < 8; ++kc) {            // K = 32
        float4 xv[4], wu[4], wv2[4];
#pragma unroll
        for (int ni = 0; ni < 4; ++ni)
            xv[ni] = *(const float4*)&zs[(ng * 4 + ni) * ZPITCH + kc * 4];
#pragma unroll
        for (int t = 0; t < 4; ++t) {
            wu[t]  = *(const float4*)&ws[(kc * 4 + t) * 64 + jg * 4];
            wv2[t] = *(const float4*)&ws[(32 + kc * 4 + t) * 64 + jg * 4];
        }
#pragma unroll
        for (int ni = 0; ni < 4; ++ni) {
            float xk[4] = {xv[ni].x, xv[ni].y, xv[ni].z, xv[ni].w};
#pragma unroll
            for (int t = 0; t < 4; ++t) {
                au[ni][0] = fmaf(xk[t], wu[t].x, au[ni][0]);
                au[ni][1] = fmaf(xk[t], wu[t].y, au[ni][1]);
                au[ni][2] = fmaf(xk[t], wu[t].z, au[ni][2]);
                au[ni][3] = fmaf(xk[t], wu[t].w, au[ni][3]);
                av[ni][0] = fmaf(xk[t], wv2[t].x, av[ni][0]);
                av[ni][1] = fmaf(xk[t], wv2[t].y, av[ni][1]);
                av[ni][2] = fmaf(xk[t], wv2[t].z, av[ni][2]);
                av[ni][3] = fmaf(xk[t], wv2[t].w, av[ni][3]);
            }
        }
    }

#pragma unroll
    for (int ni = 0; ni < 4; ++ni) {
        int node = nodeBase + ng * 4 + ni;
        if (node < N) {
            __half2* pu = (__half2*)(uv + (size_t)node * 128 + jg * 4);
            pu[0] = __floats2half2_rn(au[ni][0], au[ni][1]);
            pu[1] = __floats2half2_rn(au[ni][2], au[ni][3]);
            __half2* pv = (__half2*)(uv + (size_t)node * 128 + 64 + jg * 4);
            pv[0] = __floats2half2_rn(av[ni][0], av[ni][1]);
            pv[1] = __floats2half2_rn(av[ni][2], av[ni][3]);
        }
    }
}

// ---------------- Decode stage 2: link_pred[e] = relu(u[a]+v[b]+b1)·w2 + b2 ----------------

__global__ __launch_bounds__(256) void decode_edge(const __half* __restrict__ uv,
                                                   const int* __restrict__ eli, int EL,
                                                   const float* __restrict__ lpb1,
                                                   const float* __restrict__ lpW2,
                                                   const float* __restrict__ lpb2,
                                                   float* __restrict__ out) {
    const int sub = threadIdx.x & 15;
    float4 b1r = *(const float4*)&lpb1[sub * 4];
    float4 w2r = *(const float4*)&lpW2[sub * 4];
    const float b2v = lpb2[0];
    int e = blockIdx.x * 16 + (threadIdx.x >> 4);
    if (e >= EL) return;
    int a = eli[e], b = eli[EL + e];
    float2 ra = *(const float2*)(uv + (size_t)a * 128 + sub * 4);        // 8B: u[a] 4 halfs
    float2 rb = *(const float2*)(uv + (size_t)b * 128 + 64 + sub * 4);   // 8B: v[b] 4 halfs
    float2 a01 = __half22float2(*(const __half2*)&ra.x);
    float2 a23 = __half22float2(*(const __half2*)&ra.y);
    float2 b01 = __half22float2(*(const __half2*)&rb.x);
    float2 b23 = __half22float2(*(const __half2*)&rb.y);
    float p = fmaxf(a01.x + b01.x + b1r.x, 0.f) * w2r.x;
    p = fmaf(fmaxf(a01.y + b01.y + b1r.y, 0.f), w2r.y, p);
    p = fmaf(fmaxf(a23.x + b23.x + b1r.z, 0.f), w2r.z, p);
    p = fmaf(fmaxf(a23.y + b23.y + b1r.w, 0.f), w2r.w, p);
    p += __shfl_down(p, 8, 16);
    p += __shfl_down(p, 4, 16);
    p += __shfl_down(p, 2, 16);
    p += __shfl_down(p, 1, 16);
    if (sub == 0) out[e] = p + b2v;
}

// ---------------- launch ----------------

extern "C" void kernel_launch(void* const* d_in, const int* in_sizes, int n_in,
                              void* d_out, int out_size, void* d_ws, size_t ws_size,
                              hipStream_t stream) {
    const float* x    = (const float*)d_in[0];
    const int* ei     = (const int*)d_in[1];
    const int* eli    = (const int*)d_in[2];
    const float* W1   = (const float*)d_in[3];
    const float* b1   = (const float*)d_in[4];
    const float* W2   = (const float*)d_in[5];
    const float* b2   = (const float*)d_in[6];
    const float* W3   = (const float*)d_in[7];
    const float* b3   = (const float*)d_in[8];
    const float* lpW1 = (const float*)d_in[9];
    const float* lpb1 = (const float*)d_in[10];
    const float* lpW2 = (const float*)d_in[11];
    const float* lpb2 = (const float*)d_in[12];

    const int N  = in_sizes[0] / 128;   // 100000
    const int E  = in_sizes[1] / 2;     // 3200000
    const int EL = in_sizes[2] / 2;     // 1000000

    char* p = (char*)d_ws;
    auto alloc = [&](size_t bytes) { void* r = (void*)p; p += (bytes + 255) & ~(size_t)255; return r; };
    float* dinv     = (float*)alloc((size_t)N * 4);
    int*   offsets  = (int*)alloc((size_t)(N + 1) * 4);
    int*   bcount   = (int*)alloc(1024 * 4);
    int*   bbase    = (int*)alloc(1024 * 4);
    int*   edge_src = (int*)alloc((size_t)E * 4);
    __half* bufG    = (__half*)alloc((size_t)N * 64 * 2);   // fp16 messages h'
    float* bufZ     = (float*)alloc((size_t)N * 64 * 4);    // fp32 z1/z2
    __half* uvbuf   = (__half*)alloc((size_t)N * 128 * 2);  // fp16 uv
    int*   pairs    = (int*)uvbuf;  // alias: pairs (12.8MB) dead before gemm_uv writes uv
    int*   chist    = (int*)bufZ;   // alias: chist (2.5MB) dead before agg_pull writes bufZ

    const int* rowv = ei;        // edge_index[0] = source
    const int* colv = ei + E;    // edge_index[1] = target

    int nbuk = (N + 127) / 128;                      // 782
    int nchunk = (E + BINA_CHUNK - 1) / BINA_CHUNK;  // 782 (<=1024 required by colscan)

    bhist_kernel<<<nchunk, 512, 0, stream>>>(colv, chist, E, nbuk);
    colscan_kernel<<<nbuk, 256, 0, stream>>>(chist, bcount, nchunk, nbuk);
    bscan_kernel<<<1, 256, 0, stream>>>(bcount, bbase, nbuk, offsets, N);
    binA_kernel<<<nchunk, 512, 0, stream>>>(rowv, colv, chist, bbase, pairs, E, nbuk);
    binB_kernel<<<nbuk, 512, 0, stream>>>(pairs, bbase, offsets, dinv, edge_src, N);

    float* zout = (float*)d_out + EL;   // z lives in the output tail (float32)

    int gblocks = (N + 63) / 64;  // 1563

    // agg_pull packed: GPW = 128/F nodes per wave; 4 waves per block.
    int aggblocks64 = (N + 7) / 8;     // F=64: 2 nodes/wave * 4 waves
    int aggblocks32 = (N + 15) / 16;   // F=32: 4 nodes/wave * 4 waves

    // layer 1: x[N,128] -> bufG h' (fp16) -> bufZ (fp32, relu)
    gemm_scale<128, 64><<<gblocks, 256, 0, stream>>>(x, W1, dinv, bufG, N);
    agg_pull<64, true><<<aggblocks64, 256, 0, stream>>>(bufG, dinv, b1, edge_src, offsets, bufZ, N);
    // layer 2
    gemm_scale<64, 64><<<gblocks, 256, 0, stream>>>(bufZ, W2, dinv, bufG, N);
    agg_pull<64, true><<<aggblocks64, 256, 0, stream>>>(bufG, dinv, b2, edge_src, offsets, bufZ, N);
    // layer 3: 32-wide, write z directly into d_out tail
    gemm_scale<64, 32><<<gblocks, 128, 0, stream>>>(bufZ, W3, dinv, bufG, N);
    agg_pull<32, false><<<aggblocks32, 256, 0, stream>>>(bufG, dinv, b3, edge_src, offsets, zout, N);
    // decode: per-node uv precompute (fp16), then per-edge gather+epilogue
    gemm_uv<<<gblocks, 256, 0, stream>>>(zout, lpW1, uvbuf, N);
    decode_edge<<<(EL + 15) / 16, 256, 0, stream>>>(uvbuf, eli, EL, lpb1, lpW2, lpb2, (float*)d_out);
}

// Round 4
// 478.729 us; speedup vs baseline: 2.6430x; 2.6430x over previous
//
#include <hip/hip_runtime.h>
#include <hip/hip_bf16.h>
#include <hip/hip_fp16.h>

// MusicGNN — 3-layer GCN encoder + MLP link predictor.
// N=100000, F_IN=128, HID=64, OUT=32, E=3.2M edges, EL=1M label edges.
// Inputs: float32 (x, weights, biases), int32 (edge indices).
// Output float32: [link_pred (1M) | z (100000*32)] concatenated flat.
//
// R15: R14's __launch_bounds__(,4) VGPR cap caused catastrophic spill
// (VGPR 64, FETCH 778MB of scratch traffic, 433us/gemm). Fix is
// structural, not a cap: per-thread tile shrunk 4x4 -> 2x4 with 2x
// threads (512/block for NOUT=64), halving the live register set so the
// compiler lands ~100-130 VGPR naturally (4-5 waves/SIMD). W staged per
// K-half so layer-1 LDS is 33.8KB (4 blocks/CU). gemm_uv same treatment.
// No min-wave launch_bounds anywhere. Sort pipeline = R13 (chist/colscan).

#define BINA_CHUNK 4096

// ---------------- per-chunk bucket histogram ----------------

__global__ __launch_bounds__(512) void bhist_kernel(const int* __restrict__ colv,
                                                    int* __restrict__ chist,
                                                    int E, int nbuk) {
    __shared__ int hist[800];
    int base = blockIdx.x * BINA_CHUNK;
    int end = min(base + BINA_CHUNK, E);
    for (int i = threadIdx.x; i < nbuk; i += 512) hist[i] = 0;
    __syncthreads();
    int e = base + threadIdx.x * 4;
    for (; e + 4 <= end; e += 2048) {
        int4 c4 = *(const int4*)&colv[e];
        atomicAdd(&hist[c4.x >> 7], 1);
        atomicAdd(&hist[c4.y >> 7], 1);
        atomicAdd(&hist[c4.z >> 7], 1);
        atomicAdd(&hist[c4.w >> 7], 1);
    }
    for (; e < end; ++e) atomicAdd(&hist[colv[e] >> 7], 1);
    __syncthreads();
    for (int b = threadIdx.x; b < nbuk; b += 512)
        chist[(size_t)blockIdx.x * nbuk + b] = hist[b];
}

// ---------------- column scan: chist[c][b] -> exclusive prefix over c ----------------

__global__ __launch_bounds__(256) void colscan_kernel(int* __restrict__ chist,
                                                      int* __restrict__ bcount,
                                                      int nchunk, int nbuk) {
    __shared__ int sh[256];
    const int b = blockIdx.x;
    const int c0 = threadIdx.x * 4;
    int v[4]; int s = 0;
#pragma unroll
    for (int i = 0; i < 4; ++i) {
        int c = c0 + i;
        v[i] = (c < nchunk) ? chist[(size_t)c * nbuk + b] : 0;
        s += v[i];
    }
    sh[threadIdx.x] = s;
    __syncthreads();
#pragma unroll
    for (int off = 1; off < 256; off <<= 1) {
        int y = (threadIdx.x >= (unsigned)off) ? sh[threadIdx.x - off] : 0;
        __syncthreads();
        sh[threadIdx.x] += y;
        __syncthreads();
    }
    int ex = sh[threadIdx.x] - s;
#pragma unroll
    for (int i = 0; i < 4; ++i) {
        int c = c0 + i;
        if (c < nchunk) { chist[(size_t)c * nbuk + b] = ex; ex += v[i]; }
    }
    if (threadIdx.x == 255) bcount[b] = sh[255];
}

// ---------------- bucket scan ----------------

__global__ __launch_bounds__(256) void bscan_kernel(const int* __restrict__ bcount,
                                                    int* __restrict__ bbase,
                                                    int nbuk, int* __restrict__ offsets, int N) {
    __shared__ int sh[256];
    int base = threadIdx.x * 4;
    int v[4]; int tsum = 0;
#pragma unroll
    for (int i = 0; i < 4; ++i) { int idx = base + i; v[i] = (idx < nbuk) ? bcount[idx] : 0; tsum += v[i]; }
    sh[threadIdx.x] = tsum;
    __syncthreads();
#pragma unroll
    for (int off = 1; off < 256; off <<= 1) {
        int y = (threadIdx.x >= (unsigned)off) ? sh[threadIdx.x - off] : 0;
        __syncthreads();
        sh[threadIdx.x] += y;
        __syncthreads();
    }
    int ex = sh[threadIdx.x] - tsum;
#pragma unroll
    for (int i = 0; i < 4; ++i) {
        int idx = base + i;
        if (idx < nbuk) { bbase[idx] = ex; ex += v[i]; }
        else if (idx == nbuk) { bbase[idx] = ex; offsets[N] = ex; }  // = E
    }
}

// ---------------- Phase A: scatter into buckets (deterministic chunk bases) ----------------

__global__ __launch_bounds__(512) void binA_kernel(const int* __restrict__ rowv,
                                                   const int* __restrict__ colv,
                                                   const int* __restrict__ chist,
                                                   const int* __restrict__ bbase,
                                                   int* __restrict__ pairs,
                                                   int E, int nbuk) {
    __shared__ int pos[800];
    int base = blockIdx.x * BINA_CHUNK;
    int end = min(base + BINA_CHUNK, E);
    for (int b = threadIdx.x; b < nbuk; b += 512)
        pos[b] = bbase[b] + chist[(size_t)blockIdx.x * nbuk + b];
    __syncthreads();
    int e = base + threadIdx.x * 4;
    for (; e + 4 <= end; e += 2048) {
        int4 c4 = *(const int4*)&colv[e];
        int4 r4 = *(const int4*)&rowv[e];
        int g0 = atomicAdd(&pos[c4.x >> 7], 1); pairs[g0] = (r4.x << 7) | (c4.x & 127);
        int g1 = atomicAdd(&pos[c4.y >> 7], 1); pairs[g1] = (r4.y << 7) | (c4.y & 127);
        int g2 = atomicAdd(&pos[c4.z >> 7], 1); pairs[g2] = (r4.z << 7) | (c4.z & 127);
        int g3 = atomicAdd(&pos[c4.w >> 7], 1); pairs[g3] = (r4.w << 7) | (c4.w & 127);
    }
    for (; e < end; ++e) {
        int c = colv[e];
        int g = atomicAdd(&pos[c >> 7], 1);
        pairs[g] = (rowv[e] << 7) | (c & 127);
    }
}

// ---------------- Phase B: per bucket — node hist, scan, offsets+dinv, scatter ----------------

__global__ __launch_bounds__(512) void binB_kernel(const int* __restrict__ pairs,
                                                   const int* __restrict__ bbase,
                                                   int* __restrict__ offsets,
                                                   float* __restrict__ dinv,
                                                   int* __restrict__ edge_src, int N) {
    __shared__ int lcnt[128];
    __shared__ int sc[128];
    __shared__ int lcur[128];
    int nodeBeg = blockIdx.x << 7;
    int segBeg = bbase[blockIdx.x];
    int segEnd = bbase[blockIdx.x + 1];
    if (threadIdx.x < 128) lcnt[threadIdx.x] = 0;
    __syncthreads();
    for (int e = segBeg + threadIdx.x; e < segEnd; e += 512)
        atomicAdd(&lcnt[pairs[e] & 127], 1);
    __syncthreads();
    int v = (threadIdx.x < 128) ? lcnt[threadIdx.x] : 0;
    if (threadIdx.x < 128) sc[threadIdx.x] = v;
    __syncthreads();
    for (int off = 1; off < 128; off <<= 1) {
        int y = 0;
        if (threadIdx.x < 128 && threadIdx.x >= (unsigned)off) y = sc[threadIdx.x - off];
        __syncthreads();
        if (threadIdx.x < 128) sc[threadIdx.x] += y;
        __syncthreads();
    }
    if (threadIdx.x < 128) {
        int ex = sc[threadIdx.x] - v;
        lcur[threadIdx.x] = ex;
        int node = nodeBeg + threadIdx.x;
        if (node < N) {
            offsets[node] = segBeg + ex;
            dinv[node] = rsqrtf((float)(v + 1));
        }
    }
    __syncthreads();
    for (int e = segBeg + threadIdx.x; e < segEnd; e += 512) {
        int p = pairs[e];
        int rel = atomicAdd(&lcur[p & 127], 1);
        edge_src[segBeg + rel] = p >> 7;
    }
}

// ---------------- GEMM + dinv scale, fp16 out ----------------
// 2 nodes x 4 outs per thread; W staged per K-half; no VGPR caps.

template <int K, int NOUT>
__global__ __launch_bounds__(32 * (NOUT / 4)) void gemm_scale(const float* __restrict__ in_,
                                                              const float* __restrict__ W,
                                                              const float* __restrict__ dinv,
                                                              __half* __restrict__ out, int N) {
    constexpr int TPB = 32 * (NOUT / 4);      // 512 (NOUT=64) / 256 (NOUT=32)
    constexpr int KS = (K > 64) ? 64 : K;     // stage depth
    constexpr int XPITCH = KS + 4;
    __shared__ float xs[64 * XPITCH];
    __shared__ float ws[KS * NOUT];

    const int tid = threadIdx.x;
    const int nodeBase = blockIdx.x * 64;

    const int jg = tid % (NOUT / 4);
    const int ng = tid / (NOUT / 4);          // 0..31, 2 nodes each

    float acc[2][4];
#pragma unroll
    for (int i = 0; i < 2; ++i)
#pragma unroll
        for (int j = 0; j < 4; ++j) acc[i][j] = 0.f;

    for (int kh = 0; kh < K / KS; ++kh) {
        if (kh) __syncthreads();   // previous compute done before overwrite
        for (int i = tid; i < KS * NOUT / 4; i += TPB)
            *(float4*)&ws[i * 4] = *(const float4*)&W[(size_t)kh * KS * NOUT + i * 4];
        for (int i = tid; i < 64 * KS / 4; i += TPB) {
            int row = i / (KS / 4), c = i % (KS / 4);
            int src = nodeBase + row; if (src >= N) src = N - 1;
            *(float4*)&xs[row * XPITCH + c * 4] =
                *(const float4*)&in_[(size_t)src * K + kh * KS + c * 4];
        }
        __syncthreads();

#pragma unroll 4
        for (int kc = 0; kc < KS / 4; ++kc) {
            float4 xv[2], wv[4];
#pragma unroll
            for (int ni = 0; ni < 2; ++ni)
                xv[ni] = *(const float4*)&xs[(ng * 2 + ni) * XPITCH + kc * 4];
#pragma unroll
            for (int t = 0; t < 4; ++t)
                wv[t] = *(const float4*)&ws[(kc * 4 + t) * NOUT + jg * 4];
#pragma unroll
            for (int ni = 0; ni < 2; ++ni) {
                acc[ni][0] = fmaf(xv[ni].x, wv[0].x, acc[ni][0]);
                acc[ni][1] = fmaf(xv[ni].x, wv[0].y, acc[ni][1]);
                acc[ni][2] = fmaf(xv[ni].x, wv[0].z, acc[ni][2]);
                acc[ni][3] = fmaf(xv[ni].x, wv[0].w, acc[ni][3]);
                acc[ni][0] = fmaf(xv[ni].y, wv[1].x, acc[ni][0]);
                acc[ni][1] = fmaf(xv[ni].y, wv[1].y, acc[ni][1]);
                acc[ni][2] = fmaf(xv[ni].y, wv[1].z, acc[ni][2]);
                acc[ni][3] = fmaf(xv[ni].y, wv[1].w, acc[ni][3]);
                acc[ni][0] = fmaf(xv[ni].z, wv[2].x, acc[ni][0]);
                acc[ni][1] = fmaf(xv[ni].z, wv[2].y, acc[ni][1]);
                acc[ni][2] = fmaf(xv[ni].z, wv[2].z, acc[ni][2]);
                acc[ni][3] = fmaf(xv[ni].z, wv[2].w, acc[ni][3]);
                acc[ni][0] = fmaf(xv[ni].w, wv[3].x, acc[ni][0]);
                acc[ni][1] = fmaf(xv[ni].w, wv[3].y, acc[ni][1]);
                acc[ni][2] = fmaf(xv[ni].w, wv[3].z, acc[ni][2]);
                acc[ni][3] = fmaf(xv[ni].w, wv[3].w, acc[ni][3]);
            }
        }
    }

#pragma unroll
    for (int ni = 0; ni < 2; ++ni) {
        int node = nodeBase + ng * 2 + ni;
        if (node < N) {
            float dn = dinv[node];
            __half2* op = (__half2*)(out + (size_t)node * NOUT + jg * 4);
            op[0] = __floats2half2_rn(acc[ni][0] * dn, acc[ni][1] * dn);
            op[1] = __floats2half2_rn(acc[ni][2] * dn, acc[ni][3] * dn);
        }
    }
}

// ---------------- Pull aggregation: packed half2 gathers, fp32 accumulate ----------------

template <int F, bool RELU>
__global__ __launch_bounds__(256) void agg_pull(const __half* __restrict__ h,
                                                const float* __restrict__ dinv,
                                                const float* __restrict__ bias,
                                                const int* __restrict__ edge_src,
                                                const int* __restrict__ offsets,
                                                float* __restrict__ out, int N) {
    constexpr int LPN = F / 2;        // lanes per node
    constexpr int GPW = 64 / LPN;     // nodes per wave
    int lane = threadIdx.x & 63;
    int wave = (blockIdx.x * 256 + (int)threadIdx.x) >> 6;
    int g = lane / LPN;
    int fl = lane % LPN;              // feature-pair index
    int node = wave * GPW + g;
    if (node >= N) return;
    float dn = dinv[node];
    int beg = offsets[node], end = offsets[node + 1];
    const __half2* __restrict__ hp = (const __half2*)h;

    float2 sv = __half22float2(hp[(size_t)node * LPN + fl]);  // self-loop
    float a0x = sv.x, a0y = sv.y;
    float a1x = 0.f, a1y = 0.f, a2x = 0.f, a2y = 0.f, a3x = 0.f, a3y = 0.f;

    int j = beg;
    for (; j + 8 <= end; j += 8) {
        int s0 = edge_src[j],     s1 = edge_src[j + 1], s2 = edge_src[j + 2], s3 = edge_src[j + 3];
        int s4 = edge_src[j + 4], s5 = edge_src[j + 5], s6 = edge_src[j + 6], s7 = edge_src[j + 7];
        __half2 v0 = hp[(size_t)s0 * LPN + fl];
        __half2 v1 = hp[(size_t)s1 * LPN + fl];
        __half2 v2 = hp[(size_t)s2 * LPN + fl];
        __half2 v3 = hp[(size_t)s3 * LPN + fl];
        __half2 v4 = hp[(size_t)s4 * LPN + fl];
        __half2 v5 = hp[(size_t)s5 * LPN + fl];
        __half2 v6 = hp[(size_t)s6 * LPN + fl];
        __half2 v7 = hp[(size_t)s7 * LPN + fl];
        float2 f0 = __half22float2(v0), f1 = __half22float2(v1);
        float2 f2 = __half22float2(v2), f3 = __half22float2(v3);
        float2 f4 = __half22float2(v4), f5 = __half22float2(v5);
        float2 f6 = __half22float2(v6), f7 = __half22float2(v7);
        a0x += f0.x; a0y += f0.y; a1x += f1.x; a1y += f1.y;
        a2x += f2.x; a2y += f2.y; a3x += f3.x; a3y += f3.y;
        a0x += f4.x; a0y += f4.y; a1x += f5.x; a1y += f5.y;
        a2x += f6.x; a2y += f6.y; a3x += f7.x; a3y += f7.y;
    }
    for (; j + 2 <= end; j += 2) {
        int s0 = edge_src[j], s1 = edge_src[j + 1];
        float2 f0 = __half22float2(hp[(size_t)s0 * LPN + fl]);
        float2 f1 = __half22float2(hp[(size_t)s1 * LPN + fl]);
        a0x += f0.x; a0y += f0.y; a1x += f1.x; a1y += f1.y;
    }
    if (j < end) {
        float2 f0 = __half22float2(hp[(size_t)edge_src[j] * LPN + fl]);
        a0x += f0.x; a0y += f0.y;
    }

    float2 bv = *(const float2*)&bias[fl * 2];
    float rx = ((a0x + a1x) + (a2x + a3x)) * dn + bv.x;
    float ry = ((a0y + a1y) + (a2y + a3y)) * dn + bv.y;
    if (RELU) { rx = fmaxf(rx, 0.f); ry = fmaxf(ry, 0.f); }
    *(float2*)&out[(size_t)node * F + fl * 2] = make_float2(rx, ry);
}

// ---------------- Decode stage 1: uv[n] = [z@W1_top | z@W1_bot] (fp16 out) ----------------
// 2 nodes per thread, 512 threads.

__global__ __launch_bounds__(512) void gemm_uv(const float* __restrict__ z,   // [N,32]
                                               const float* __restrict__ W1,  // [64,64]
                                               __half* __restrict__ uv, int N) {
    constexpr int ZPITCH = 36;
    __shared__ float zs[64 * ZPITCH];
    __shared__ float ws[64 * 64];
    const int tid = threadIdx.x;
    const int nodeBase = blockIdx.x * 64;

    for (int i = tid; i < 64 * 64 / 4; i += 512)
        *(float4*)&ws[i * 4] = *(const float4*)&W1[i * 4];
    for (int i = tid; i < 64 * 8; i += 512) {
        int row = i / 8, c = i % 8;
        int src = nodeBase + row; if (src >= N) src = N - 1;
        *(float4*)&zs[row * ZPITCH + c * 4] = *(const float4*)&z[(size_t)src * 32 + c * 4];
    }
    __syncthreads();

    const int jg = tid % 16;
    const int ng = tid / 16;     // 0..31, 2 nodes each

    float au[2][4], av[2][4];
#pragma unroll
    for (int i = 0; i < 2; ++i)
#pragma unroll
        for (int j = 0; j < 4; ++j) { au[i][j] = 0.f; av[i][j] = 0.f; }

#pragma unroll 4
    for (int kc = 0; kc < 8; ++kc) {            // K = 32
        float4 xv[2], wu[4], wv2[4];
#pragma unroll
        for (int ni = 0; ni < 2; ++ni)
            xv[ni] = *(const float4*)&zs[(ng * 2 + ni) * ZPITCH + kc * 4];
#pragma unroll
        for (int t = 0; t < 4; ++t) {
            wu[t]  = *(const float4*)&ws[(kc * 4 + t) * 64 + jg * 4];
            wv2[t] = *(const float4*)&ws[(32 + kc * 4 + t) * 64 + jg * 4];
        }
#pragma unroll
        for (int ni = 0; ni < 2; ++ni) {
            float xk[4] = {xv[ni].x, xv[ni].y, xv[ni].z, xv[ni].w};
#pragma unroll
            for (int t = 0; t < 4; ++t) {
                au[ni][0] = fmaf(xk[t], wu[t].x, au[ni][0]);
                au[ni][1] = fmaf(xk[t], wu[t].y, au[ni][1]);
                au[ni][2] = fmaf(xk[t], wu[t].z, au[ni][2]);
                au[ni][3] = fmaf(xk[t], wu[t].w, au[ni][3]);
                av[ni][0] = fmaf(xk[t], wv2[t].x, av[ni][0]);
                av[ni][1] = fmaf(xk[t], wv2[t].y, av[ni][1]);
                av[ni][2] = fmaf(xk[t], wv2[t].z, av[ni][2]);
                av[ni][3] = fmaf(xk[t], wv2[t].w, av[ni][3]);
            }
        }
    }

#pragma unroll
    for (int ni = 0; ni < 2; ++ni) {
        int node = nodeBase + ng * 2 + ni;
        if (node < N) {
            __half2* pu = (__half2*)(uv + (size_t)node * 128 + jg * 4);
            pu[0] = __floats2half2_rn(au[ni][0], au[ni][1]);
            pu[1] = __floats2half2_rn(au[ni][2], au[ni][3]);
            __half2* pv = (__half2*)(uv + (size_t)node * 128 + 64 + jg * 4);
            pv[0] = __floats2half2_rn(av[ni][0], av[ni][1]);
            pv[1] = __floats2half2_rn(av[ni][2], av[ni][3]);
        }
    }
}

// ---------------- Decode stage 2: link_pred[e] = relu(u[a]+v[b]+b1)·w2 + b2 ----------------

__global__ __launch_bounds__(256) void decode_edge(const __half* __restrict__ uv,
                                                   const int* __restrict__ eli, int EL,
                                                   const float* __restrict__ lpb1,
                                                   const float* __restrict__ lpW2,
                                                   const float* __restrict__ lpb2,
                                                   float* __restrict__ out) {
    const int sub = threadIdx.x & 15;
    float4 b1r = *(const float4*)&lpb1[sub * 4];
    float4 w2r = *(const float4*)&lpW2[sub * 4];
    const float b2v = lpb2[0];
    int e = blockIdx.x * 16 + (threadIdx.x >> 4);
    if (e >= EL) return;
    int a = eli[e], b = eli[EL + e];
    float2 ra = *(const float2*)(uv + (size_t)a * 128 + sub * 4);        // 8B: u[a] 4 halfs
    float2 rb = *(const float2*)(uv + (size_t)b * 128 + 64 + sub * 4);   // 8B: v[b] 4 halfs
    float2 a01 = __half22float2(*(const __half2*)&ra.x);
    float2 a23 = __half22float2(*(const __half2*)&ra.y);
    float2 b01 = __half22float2(*(const __half2*)&rb.x);
    float2 b23 = __half22float2(*(const __half2*)&rb.y);
    float p = fmaxf(a01.x + b01.x + b1r.x, 0.f) * w2r.x;
    p = fmaf(fmaxf(a01.y + b01.y + b1r.y, 0.f), w2r.y, p);
    p = fmaf(fmaxf(a23.x + b23.x + b1r.z, 0.f), w2r.z, p);
    p = fmaf(fmaxf(a23.y + b23.y + b1r.w, 0.f), w2r.w, p);
    p += __shfl_down(p, 8, 16);
    p += __shfl_down(p, 4, 16);
    p += __shfl_down(p, 2, 16);
    p += __shfl_down(p, 1, 16);
    if (sub == 0) out[e] = p + b2v;
}

// ---------------- launch ----------------

extern "C" void kernel_launch(void* const* d_in, const int* in_sizes, int n_in,
                              void* d_out, int out_size, void* d_ws, size_t ws_size,
                              hipStream_t stream) {
    const float* x    = (const float*)d_in[0];
    const int* ei     = (const int*)d_in[1];
    const int* eli    = (const int*)d_in[2];
    const float* W1   = (const float*)d_in[3];
    const float* b1   = (const float*)d_in[4];
    const float* W2   = (const float*)d_in[5];
    const float* b2   = (const float*)d_in[6];
    const float* W3   = (const float*)d_in[7];
    const float* b3   = (const float*)d_in[8];
    const float* lpW1 = (const float*)d_in[9];
    const float* lpb1 = (const float*)d_in[10];
    const float* lpW2 = (const float*)d_in[11];
    const float* lpb2 = (const float*)d_in[12];

    const int N  = in_sizes[0] / 128;   // 100000
    const int E  = in_sizes[1] / 2;     // 3200000
    const int EL = in_sizes[2] / 2;     // 1000000

    char* p = (char*)d_ws;
    auto alloc = [&](size_t bytes) { void* r = (void*)p; p += (bytes + 255) & ~(size_t)255; return r; };
    float* dinv     = (float*)alloc((size_t)N * 4);
    int*   offsets  = (int*)alloc((size_t)(N + 1) * 4);
    int*   bcount   = (int*)alloc(1024 * 4);
    int*   bbase    = (int*)alloc(1024 * 4);
    int*   edge_src = (int*)alloc((size_t)E * 4);
    __half* bufG    = (__half*)alloc((size_t)N * 64 * 2);   // fp16 messages h'
    float* bufZ     = (float*)alloc((size_t)N * 64 * 4);    // fp32 z1/z2
    __half* uvbuf   = (__half*)alloc((size_t)N * 128 * 2);  // fp16 uv
    int*   pairs    = (int*)uvbuf;  // alias: pairs (12.8MB) dead before gemm_uv writes uv
    int*   chist    = (int*)bufZ;   // alias: chist (2.5MB) dead before agg_pull writes bufZ

    const int* rowv = ei;        // edge_index[0] = source
    const int* colv = ei + E;    // edge_index[1] = target

    int nbuk = (N + 127) / 128;                      // 782
    int nchunk = (E + BINA_CHUNK - 1) / BINA_CHUNK;  // 782 (<=1024 required by colscan)

    bhist_kernel<<<nchunk, 512, 0, stream>>>(colv, chist, E, nbuk);
    colscan_kernel<<<nbuk, 256, 0, stream>>>(chist, bcount, nchunk, nbuk);
    bscan_kernel<<<1, 256, 0, stream>>>(bcount, bbase, nbuk, offsets, N);
    binA_kernel<<<nchunk, 512, 0, stream>>>(rowv, colv, chist, bbase, pairs, E, nbuk);
    binB_kernel<<<nbuk, 512, 0, stream>>>(pairs, bbase, offsets, dinv, edge_src, N);

    float* zout = (float*)d_out + EL;   // z lives in the output tail (float32)

    int gblocks = (N + 63) / 64;  // 1563

    // agg_pull packed: GPW = 128/F nodes per wave; 4 waves per block.
    int aggblocks64 = (N + 7) / 8;     // F=64: 2 nodes/wave * 4 waves
    int aggblocks32 = (N + 15) / 16;   // F=32: 4 nodes/wave * 4 waves

    // layer 1: x[N,128] -> bufG h' (fp16) -> bufZ (fp32, relu)
    gemm_scale<128, 64><<<gblocks, 512, 0, stream>>>(x, W1, dinv, bufG, N);
    agg_pull<64, true><<<aggblocks64, 256, 0, stream>>>(bufG, dinv, b1, edge_src, offsets, bufZ, N);
    // layer 2
    gemm_scale<64, 64><<<gblocks, 512, 0, stream>>>(bufZ, W2, dinv, bufG, N);
    agg_pull<64, true><<<aggblocks64, 256, 0, stream>>>(bufG, dinv, b2, edge_src, offsets, bufZ, N);
    // layer 3: 32-wide, write z directly into d_out tail
    gemm_scale<64, 32><<<gblocks, 256, 0, stream>>>(bufZ, W3, dinv, bufG, N);
    agg_pull<32, false><<<aggblocks32, 256, 0, stream>>>(bufG, dinv, b3, edge_src, offsets, zout, N);
    // decode: per-node uv precompute (fp16), then per-edge gather+epilogue
    gemm_uv<<<gblocks, 512, 0, stream>>>(zout, lpW1, uvbuf, N);
    decode_edge<<<(EL + 15) / 16, 256, 0, stream>>>(uvbuf, eli, EL, lpb1, lpW2, lpb2, (float*)d_out);
}

// Round 5
// 462.877 us; speedup vs baseline: 2.7335x; 1.0342x over previous
//
#include <hip/hip_runtime.h>
#include <hip/hip_bf16.h>
#include <hip/hip_fp16.h>

// MusicGNN — 3-layer GCN encoder + MLP link predictor.
// N=100000, F_IN=128, HID=64, OUT=32, E=3.2M edges, EL=1M label edges.
// Inputs: float32 (x, weights, biases), int32 (edge indices).
// Output float32: [link_pred (1M) | z (100000*32)] concatenated flat.
//
// R16: (a) BINA_CHUNK 4096->8192: (chunk,bucket) write slices double to
// ~42B, halving binA's 5x dirty-line write amplification on pairs;
// chist shrinks 2.4->1.2MB. (b) decode_edge rewritten at 8 lanes/edge
// with float4 (16B) uv loads: halves per-edge VMEM instrs, shuffle tree
// 3 deep. This doubles as a regime probe: if decode improves, the gather
// kernels are issue/latency-bound and agg_pull gets the same treatment
// next; if flat, they're fabric-random-bound (structural).
// GEMMs = R15 (2x4 tile, no caps). Sort pipeline otherwise = R13.

#define BINA_CHUNK 8192

// ---------------- per-chunk bucket histogram ----------------

__global__ __launch_bounds__(512) void bhist_kernel(const int* __restrict__ colv,
                                                    int* __restrict__ chist,
                                                    int E, int nbuk) {
    __shared__ int hist[800];
    int base = blockIdx.x * BINA_CHUNK;
    int end = min(base + BINA_CHUNK, E);
    for (int i = threadIdx.x; i < nbuk; i += 512) hist[i] = 0;
    __syncthreads();
    int e = base + threadIdx.x * 4;
    for (; e + 4 <= end; e += 2048) {
        int4 c4 = *(const int4*)&colv[e];
        atomicAdd(&hist[c4.x >> 7], 1);
        atomicAdd(&hist[c4.y >> 7], 1);
        atomicAdd(&hist[c4.z >> 7], 1);
        atomicAdd(&hist[c4.w >> 7], 1);
    }
    for (; e < end; ++e) atomicAdd(&hist[colv[e] >> 7], 1);
    __syncthreads();
    for (int b = threadIdx.x; b < nbuk; b += 512)
        chist[(size_t)blockIdx.x * nbuk + b] = hist[b];
}

// ---------------- column scan: chist[c][b] -> exclusive prefix over c ----------------

__global__ __launch_bounds__(256) void colscan_kernel(int* __restrict__ chist,
                                                      int* __restrict__ bcount,
                                                      int nchunk, int nbuk) {
    __shared__ int sh[256];
    const int b = blockIdx.x;
    const int c0 = threadIdx.x * 4;
    int v[4]; int s = 0;
#pragma unroll
    for (int i = 0; i < 4; ++i) {
        int c = c0 + i;
        v[i] = (c < nchunk) ? chist[(size_t)c * nbuk + b] : 0;
        s += v[i];
    }
    sh[threadIdx.x] = s;
    __syncthreads();
#pragma unroll
    for (int off = 1; off < 256; off <<= 1) {
        int y = (threadIdx.x >= (unsigned)off) ? sh[threadIdx.x - off] : 0;
        __syncthreads();
        sh[threadIdx.x] += y;
        __syncthreads();
    }
    int ex = sh[threadIdx.x] - s;
#pragma unroll
    for (int i = 0; i < 4; ++i) {
        int c = c0 + i;
        if (c < nchunk) { chist[(size_t)c * nbuk + b] = ex; ex += v[i]; }
    }
    if (threadIdx.x == 255) bcount[b] = sh[255];
}

// ---------------- bucket scan ----------------

__global__ __launch_bounds__(256) void bscan_kernel(const int* __restrict__ bcount,
                                                    int* __restrict__ bbase,
                                                    int nbuk, int* __restrict__ offsets, int N) {
    __shared__ int sh[256];
    int base = threadIdx.x * 4;
    int v[4]; int tsum = 0;
#pragma unroll
    for (int i = 0; i < 4; ++i) { int idx = base + i; v[i] = (idx < nbuk) ? bcount[idx] : 0; tsum += v[i]; }
    sh[threadIdx.x] = tsum;
    __syncthreads();
#pragma unroll
    for (int off = 1; off < 256; off <<= 1) {
        int y = (threadIdx.x >= (unsigned)off) ? sh[threadIdx.x - off] : 0;
        __syncthreads();
        sh[threadIdx.x] += y;
        __syncthreads();
    }
    int ex = sh[threadIdx.x] - tsum;
#pragma unroll
    for (int i = 0; i < 4; ++i) {
        int idx = base + i;
        if (idx < nbuk) { bbase[idx] = ex; ex += v[i]; }
        else if (idx == nbuk) { bbase[idx] = ex; offsets[N] = ex; }  // = E
    }
}

// ---------------- Phase A: scatter into buckets (deterministic chunk bases) ----------------

__global__ __launch_bounds__(512) void binA_kernel(const int* __restrict__ rowv,
                                                   const int* __restrict__ colv,
                                                   const int* __restrict__ chist,
                                                   const int* __restrict__ bbase,
                                                   int* __restrict__ pairs,
                                                   int E, int nbuk) {
    __shared__ int pos[800];
    int base = blockIdx.x * BINA_CHUNK;
    int end = min(base + BINA_CHUNK, E);
    for (int b = threadIdx.x; b < nbuk; b += 512)
        pos[b] = bbase[b] + chist[(size_t)blockIdx.x * nbuk + b];
    __syncthreads();
    int e = base + threadIdx.x * 4;
    for (; e + 4 <= end; e += 2048) {
        int4 c4 = *(const int4*)&colv[e];
        int4 r4 = *(const int4*)&rowv[e];
        int g0 = atomicAdd(&pos[c4.x >> 7], 1); pairs[g0] = (r4.x << 7) | (c4.x & 127);
        int g1 = atomicAdd(&pos[c4.y >> 7], 1); pairs[g1] = (r4.y << 7) | (c4.y & 127);
        int g2 = atomicAdd(&pos[c4.z >> 7], 1); pairs[g2] = (r4.z << 7) | (c4.z & 127);
        int g3 = atomicAdd(&pos[c4.w >> 7], 1); pairs[g3] = (r4.w << 7) | (c4.w & 127);
    }
    for (; e < end; ++e) {
        int c = colv[e];
        int g = atomicAdd(&pos[c >> 7], 1);
        pairs[g] = (rowv[e] << 7) | (c & 127);
    }
}

// ---------------- Phase B: per bucket — node hist, scan, offsets+dinv, scatter ----------------

__global__ __launch_bounds__(512) void binB_kernel(const int* __restrict__ pairs,
                                                   const int* __restrict__ bbase,
                                                   int* __restrict__ offsets,
                                                   float* __restrict__ dinv,
                                                   int* __restrict__ edge_src, int N) {
    __shared__ int lcnt[128];
    __shared__ int sc[128];
    __shared__ int lcur[128];
    int nodeBeg = blockIdx.x << 7;
    int segBeg = bbase[blockIdx.x];
    int segEnd = bbase[blockIdx.x + 1];
    if (threadIdx.x < 128) lcnt[threadIdx.x] = 0;
    __syncthreads();
    for (int e = segBeg + threadIdx.x; e < segEnd; e += 512)
        atomicAdd(&lcnt[pairs[e] & 127], 1);
    __syncthreads();
    int v = (threadIdx.x < 128) ? lcnt[threadIdx.x] : 0;
    if (threadIdx.x < 128) sc[threadIdx.x] = v;
    __syncthreads();
    for (int off = 1; off < 128; off <<= 1) {
        int y = 0;
        if (threadIdx.x < 128 && threadIdx.x >= (unsigned)off) y = sc[threadIdx.x - off];
        __syncthreads();
        if (threadIdx.x < 128) sc[threadIdx.x] += y;
        __syncthreads();
    }
    if (threadIdx.x < 128) {
        int ex = sc[threadIdx.x] - v;
        lcur[threadIdx.x] = ex;
        int node = nodeBeg + threadIdx.x;
        if (node < N) {
            offsets[node] = segBeg + ex;
            dinv[node] = rsqrtf((float)(v + 1));
        }
    }
    __syncthreads();
    for (int e = segBeg + threadIdx.x; e < segEnd; e += 512) {
        int p = pairs[e];
        int rel = atomicAdd(&lcur[p & 127], 1);
        edge_src[segBeg + rel] = p >> 7;
    }
}

// ---------------- GEMM + dinv scale, fp16 out ----------------
// 2 nodes x 4 outs per thread; W staged per K-half; no VGPR caps.

template <int K, int NOUT>
__global__ __launch_bounds__(32 * (NOUT / 4)) void gemm_scale(const float* __restrict__ in_,
                                                              const float* __restrict__ W,
                                                              const float* __restrict__ dinv,
                                                              __half* __restrict__ out, int N) {
    constexpr int TPB = 32 * (NOUT / 4);      // 512 (NOUT=64) / 256 (NOUT=32)
    constexpr int KS = (K > 64) ? 64 : K;     // stage depth
    constexpr int XPITCH = KS + 4;
    __shared__ float xs[64 * XPITCH];
    __shared__ float ws[KS * NOUT];

    const int tid = threadIdx.x;
    const int nodeBase = blockIdx.x * 64;

    const int jg = tid % (NOUT / 4);
    const int ng = tid / (NOUT / 4);          // 0..31, 2 nodes each

    float acc[2][4];
#pragma unroll
    for (int i = 0; i < 2; ++i)
#pragma unroll
        for (int j = 0; j < 4; ++j) acc[i][j] = 0.f;

    for (int kh = 0; kh < K / KS; ++kh) {
        if (kh) __syncthreads();   // previous compute done before overwrite
        for (int i = tid; i < KS * NOUT / 4; i += TPB)
            *(float4*)&ws[i * 4] = *(const float4*)&W[(size_t)kh * KS * NOUT + i * 4];
        for (int i = tid; i < 64 * KS / 4; i += TPB) {
            int row = i / (KS / 4), c = i % (KS / 4);
            int src = nodeBase + row; if (src >= N) src = N - 1;
            *(float4*)&xs[row * XPITCH + c * 4] =
                *(const float4*)&in_[(size_t)src * K + kh * KS + c * 4];
        }
        __syncthreads();

#pragma unroll 4
        for (int kc = 0; kc < KS / 4; ++kc) {
            float4 xv[2], wv[4];
#pragma unroll
            for (int ni = 0; ni < 2; ++ni)
                xv[ni] = *(const float4*)&xs[(ng * 2 + ni) * XPITCH + kc * 4];
#pragma unroll
            for (int t = 0; t < 4; ++t)
                wv[t] = *(const float4*)&ws[(kc * 4 + t) * NOUT + jg * 4];
#pragma unroll
            for (int ni = 0; ni < 2; ++ni) {
                acc[ni][0] = fmaf(xv[ni].x, wv[0].x, acc[ni][0]);
                acc[ni][1] = fmaf(xv[ni].x, wv[0].y, acc[ni][1]);
                acc[ni][2] = fmaf(xv[ni].x, wv[0].z, acc[ni][2]);
                acc[ni][3] = fmaf(xv[ni].x, wv[0].w, acc[ni][3]);
                acc[ni][0] = fmaf(xv[ni].y, wv[1].x, acc[ni][0]);
                acc[ni][1] = fmaf(xv[ni].y, wv[1].y, acc[ni][1]);
                acc[ni][2] = fmaf(xv[ni].y, wv[1].z, acc[ni][2]);
                acc[ni][3] = fmaf(xv[ni].y, wv[1].w, acc[ni][3]);
                acc[ni][0] = fmaf(xv[ni].z, wv[2].x, acc[ni][0]);
                acc[ni][1] = fmaf(xv[ni].z, wv[2].y, acc[ni][1]);
                acc[ni][2] = fmaf(xv[ni].z, wv[2].z, acc[ni][2]);
                acc[ni][3] = fmaf(xv[ni].z, wv[2].w, acc[ni][3]);
                acc[ni][0] = fmaf(xv[ni].w, wv[3].x, acc[ni][0]);
                acc[ni][1] = fmaf(xv[ni].w, wv[3].y, acc[ni][1]);
                acc[ni][2] = fmaf(xv[ni].w, wv[3].z, acc[ni][2]);
                acc[ni][3] = fmaf(xv[ni].w, wv[3].w, acc[ni][3]);
            }
        }
    }

#pragma unroll
    for (int ni = 0; ni < 2; ++ni) {
        int node = nodeBase + ng * 2 + ni;
        if (node < N) {
            float dn = dinv[node];
            __half2* op = (__half2*)(out + (size_t)node * NOUT + jg * 4);
            op[0] = __floats2half2_rn(acc[ni][0] * dn, acc[ni][1] * dn);
            op[1] = __floats2half2_rn(acc[ni][2] * dn, acc[ni][3] * dn);
        }
    }
}

// ---------------- Pull aggregation: packed half2 gathers, fp32 accumulate ----------------

template <int F, bool RELU>
__global__ __launch_bounds__(256) void agg_pull(const __half* __restrict__ h,
                                                const float* __restrict__ dinv,
                                                const float* __restrict__ bias,
                                                const int* __restrict__ edge_src,
                                                const int* __restrict__ offsets,
                                                float* __restrict__ out, int N) {
    constexpr int LPN = F / 2;        // lanes per node
    constexpr int GPW = 64 / LPN;     // nodes per wave
    int lane = threadIdx.x & 63;
    int wave = (blockIdx.x * 256 + (int)threadIdx.x) >> 6;
    int g = lane / LPN;
    int fl = lane % LPN;              // feature-pair index
    int node = wave * GPW + g;
    if (node >= N) return;
    float dn = dinv[node];
    int beg = offsets[node], end = offsets[node + 1];
    const __half2* __restrict__ hp = (const __half2*)h;

    float2 sv = __half22float2(hp[(size_t)node * LPN + fl]);  // self-loop
    float a0x = sv.x, a0y = sv.y;
    float a1x = 0.f, a1y = 0.f, a2x = 0.f, a2y = 0.f, a3x = 0.f, a3y = 0.f;

    int j = beg;
    for (; j + 8 <= end; j += 8) {
        int s0 = edge_src[j],     s1 = edge_src[j + 1], s2 = edge_src[j + 2], s3 = edge_src[j + 3];
        int s4 = edge_src[j + 4], s5 = edge_src[j + 5], s6 = edge_src[j + 6], s7 = edge_src[j + 7];
        __half2 v0 = hp[(size_t)s0 * LPN + fl];
        __half2 v1 = hp[(size_t)s1 * LPN + fl];
        __half2 v2 = hp[(size_t)s2 * LPN + fl];
        __half2 v3 = hp[(size_t)s3 * LPN + fl];
        __half2 v4 = hp[(size_t)s4 * LPN + fl];
        __half2 v5 = hp[(size_t)s5 * LPN + fl];
        __half2 v6 = hp[(size_t)s6 * LPN + fl];
        __half2 v7 = hp[(size_t)s7 * LPN + fl];
        float2 f0 = __half22float2(v0), f1 = __half22float2(v1);
        float2 f2 = __half22float2(v2), f3 = __half22float2(v3);
        float2 f4 = __half22float2(v4), f5 = __half22float2(v5);
        float2 f6 = __half22float2(v6), f7 = __half22float2(v7);
        a0x += f0.x; a0y += f0.y; a1x += f1.x; a1y += f1.y;
        a2x += f2.x; a2y += f2.y; a3x += f3.x; a3y += f3.y;
        a0x += f4.x; a0y += f4.y; a1x += f5.x; a1y += f5.y;
        a2x += f6.x; a2y += f6.y; a3x += f7.x; a3y += f7.y;
    }
    for (; j + 2 <= end; j += 2) {
        int s0 = edge_src[j], s1 = edge_src[j + 1];
        float2 f0 = __half22float2(hp[(size_t)s0 * LPN + fl]);
        float2 f1 = __half22float2(hp[(size_t)s1 * LPN + fl]);
        a0x += f0.x; a0y += f0.y; a1x += f1.x; a1y += f1.y;
    }
    if (j < end) {
        float2 f0 = __half22float2(hp[(size_t)edge_src[j] * LPN + fl]);
        a0x += f0.x; a0y += f0.y;
    }

    float2 bv = *(const float2*)&bias[fl * 2];
    float rx = ((a0x + a1x) + (a2x + a3x)) * dn + bv.x;
    float ry = ((a0y + a1y) + (a2y + a3y)) * dn + bv.y;
    if (RELU) { rx = fmaxf(rx, 0.f); ry = fmaxf(ry, 0.f); }
    *(float2*)&out[(size_t)node * F + fl * 2] = make_float2(rx, ry);
}

// ---------------- Decode stage 1: uv[n] = [z@W1_top | z@W1_bot] (fp16 out) ----------------
// 2 nodes per thread, 512 threads.

__global__ __launch_bounds__(512) void gemm_uv(const float* __restrict__ z,   // [N,32]
                                               const float* __restrict__ W1,  // [64,64]
                                               __half* __restrict__ uv, int N) {
    constexpr int ZPITCH = 36;
    __shared__ float zs[64 * ZPITCH];
    __shared__ float ws[64 * 64];
    const int tid = threadIdx.x;
    const int nodeBase = blockIdx.x * 64;

    for (int i = tid; i < 64 * 64 / 4; i += 512)
        *(float4*)&ws[i * 4] = *(const float4*)&W1[i * 4];
    for (int i = tid; i < 64 * 8; i += 512) {
        int row = i / 8, c = i % 8;
        int src = nodeBase + row; if (src >= N) src = N - 1;
        *(float4*)&zs[row * ZPITCH + c * 4] = *(const float4*)&z[(size_t)src * 32 + c * 4];
    }
    __syncthreads();

    const int jg = tid % 16;
    const int ng = tid / 16;     // 0..31, 2 nodes each

    float au[2][4], av[2][4];
#pragma unroll
    for (int i = 0; i < 2; ++i)
#pragma unroll
        for (int j = 0; j < 4; ++j) { au[i][j] = 0.f; av[i][j] = 0.f; }

#pragma unroll 4
    for (int kc = 0; kc < 8; ++kc) {            // K = 32
        float4 xv[2], wu[4], wv2[4];
#pragma unroll
        for (int ni = 0; ni < 2; ++ni)
            xv[ni] = *(const float4*)&zs[(ng * 2 + ni) * ZPITCH + kc * 4];
#pragma unroll
        for (int t = 0; t < 4; ++t) {
            wu[t]  = *(const float4*)&ws[(kc * 4 + t) * 64 + jg * 4];
            wv2[t] = *(const float4*)&ws[(32 + kc * 4 + t) * 64 + jg * 4];
        }
#pragma unroll
        for (int ni = 0; ni < 2; ++ni) {
            float xk[4] = {xv[ni].x, xv[ni].y, xv[ni].z, xv[ni].w};
#pragma unroll
            for (int t = 0; t < 4; ++t) {
                au[ni][0] = fmaf(xk[t], wu[t].x, au[ni][0]);
                au[ni][1] = fmaf(xk[t], wu[t].y, au[ni][1]);
                au[ni][2] = fmaf(xk[t], wu[t].z, au[ni][2]);
                au[ni][3] = fmaf(xk[t], wu[t].w, au[ni][3]);
                av[ni][0] = fmaf(xk[t], wv2[t].x, av[ni][0]);
                av[ni][1] = fmaf(xk[t], wv2[t].y, av[ni][1]);
                av[ni][2] = fmaf(xk[t], wv2[t].z, av[ni][2]);
                av[ni][3] = fmaf(xk[t], wv2[t].w, av[ni][3]);
            }
        }
    }

#pragma unroll
    for (int ni = 0; ni < 2; ++ni) {
        int node = nodeBase + ng * 2 + ni;
        if (node < N) {
            __half2* pu = (__half2*)(uv + (size_t)node * 128 + jg * 4);
            pu[0] = __floats2half2_rn(au[ni][0], au[ni][1]);
            pu[1] = __floats2half2_rn(au[ni][2], au[ni][3]);
            __half2* pv = (__half2*)(uv + (size_t)node * 128 + 64 + jg * 4);
            pv[0] = __floats2half2_rn(av[ni][0], av[ni][1]);
            pv[1] = __floats2half2_rn(av[ni][2], av[ni][3]);
        }
    }
}

// ---------------- Decode stage 2: link_pred[e] = relu(u[a]+v[b]+b1)·w2 + b2 ----------------
// 8 lanes/edge, float4 (16B) uv loads, 3-deep shuffle reduce.

__global__ __launch_bounds__(256) void decode_edge(const __half* __restrict__ uv,
                                                   const int* __restrict__ eli, int EL,
                                                   const float* __restrict__ lpb1,
                                                   const float* __restrict__ lpW2,
                                                   const float* __restrict__ lpb2,
                                                   float* __restrict__ out) {
    const int sub = threadIdx.x & 7;
    float4 b1a = *(const float4*)&lpb1[sub * 8];
    float4 b1b = *(const float4*)&lpb1[sub * 8 + 4];
    float4 w2a = *(const float4*)&lpW2[sub * 8];
    float4 w2b = *(const float4*)&lpW2[sub * 8 + 4];
    const float b2v = lpb2[0];
    int e = blockIdx.x * 32 + (threadIdx.x >> 3);
    if (e >= EL) return;
    int a = eli[e], b = eli[EL + e];
    float4 ra = *(const float4*)(uv + (size_t)a * 128 + sub * 8);        // 16B: 8 halfs of u[a]
    float4 rb = *(const float4*)(uv + (size_t)b * 128 + 64 + sub * 8);   // 16B: 8 halfs of v[b]
    float2 a01 = __half22float2(*(const __half2*)&ra.x);
    float2 a23 = __half22float2(*(const __half2*)&ra.y);
    float2 a45 = __half22float2(*(const __half2*)&ra.z);
    float2 a67 = __half22float2(*(const __half2*)&ra.w);
    float2 b01 = __half22float2(*(const __half2*)&rb.x);
    float2 b23 = __half22float2(*(const __half2*)&rb.y);
    float2 b45 = __half22float2(*(const __half2*)&rb.z);
    float2 b67 = __half22float2(*(const __half2*)&rb.w);
    float p = fmaxf(a01.x + b01.x + b1a.x, 0.f) * w2a.x;
    p = fmaf(fmaxf(a01.y + b01.y + b1a.y, 0.f), w2a.y, p);
    p = fmaf(fmaxf(a23.x + b23.x + b1a.z, 0.f), w2a.z, p);
    p = fmaf(fmaxf(a23.y + b23.y + b1a.w, 0.f), w2a.w, p);
    p = fmaf(fmaxf(a45.x + b45.x + b1b.x, 0.f), w2b.x, p);
    p = fmaf(fmaxf(a45.y + b45.y + b1b.y, 0.f), w2b.y, p);
    p = fmaf(fmaxf(a67.x + b67.x + b1b.z, 0.f), w2b.z, p);
    p = fmaf(fmaxf(a67.y + b67.y + b1b.w, 0.f), w2b.w, p);
    p += __shfl_down(p, 4, 8);
    p += __shfl_down(p, 2, 8);
    p += __shfl_down(p, 1, 8);
    if (sub == 0) out[e] = p + b2v;
}

// ---------------- launch ----------------

extern "C" void kernel_launch(void* const* d_in, const int* in_sizes, int n_in,
                              void* d_out, int out_size, void* d_ws, size_t ws_size,
                              hipStream_t stream) {
    const float* x    = (const float*)d_in[0];
    const int* ei     = (const int*)d_in[1];
    const int* eli    = (const int*)d_in[2];
    const float* W1   = (const float*)d_in[3];
    const float* b1   = (const float*)d_in[4];
    const float* W2   = (const float*)d_in[5];
    const float* b2   = (const float*)d_in[6];
    const float* W3   = (const float*)d_in[7];
    const float* b3   = (const float*)d_in[8];
    const float* lpW1 = (const float*)d_in[9];
    const float* lpb1 = (const float*)d_in[10];
    const float* lpW2 = (const float*)d_in[11];
    const float* lpb2 = (const float*)d_in[12];

    const int N  = in_sizes[0] / 128;   // 100000
    const int E  = in_sizes[1] / 2;     // 3200000
    const int EL = in_sizes[2] / 2;     // 1000000

    char* p = (char*)d_ws;
    auto alloc = [&](size_t bytes) { void* r = (void*)p; p += (bytes + 255) & ~(size_t)255; return r; };
    float* dinv     = (float*)alloc((size_t)N * 4);
    int*   offsets  = (int*)alloc((size_t)(N + 1) * 4);
    int*   bcount   = (int*)alloc(1024 * 4);
    int*   bbase    = (int*)alloc(1024 * 4);
    int*   edge_src = (int*)alloc((size_t)E * 4);
    __half* bufG    = (__half*)alloc((size_t)N * 64 * 2);   // fp16 messages h'
    float* bufZ     = (float*)alloc((size_t)N * 64 * 4);    // fp32 z1/z2
    __half* uvbuf   = (__half*)alloc((size_t)N * 128 * 2);  // fp16 uv
    int*   pairs    = (int*)uvbuf;  // alias: pairs (12.8MB) dead before gemm_uv writes uv
    int*   chist    = (int*)bufZ;   // alias: chist (1.3MB) dead before agg_pull writes bufZ

    const int* rowv = ei;        // edge_index[0] = source
    const int* colv = ei + E;    // edge_index[1] = target

    int nbuk = (N + 127) / 128;                      // 782
    int nchunk = (E + BINA_CHUNK - 1) / BINA_CHUNK;  // 391 (<=1024 required by colscan)

    bhist_kernel<<<nchunk, 512, 0, stream>>>(colv, chist, E, nbuk);
    colscan_kernel<<<nbuk, 256, 0, stream>>>(chist, bcount, nchunk, nbuk);
    bscan_kernel<<<1, 256, 0, stream>>>(bcount, bbase, nbuk, offsets, N);
    binA_kernel<<<nchunk, 512, 0, stream>>>(rowv, colv, chist, bbase, pairs, E, nbuk);
    binB_kernel<<<nbuk, 512, 0, stream>>>(pairs, bbase, offsets, dinv, edge_src, N);

    float* zout = (float*)d_out + EL;   // z lives in the output tail (float32)

    int gblocks = (N + 63) / 64;  // 1563

    // agg_pull packed: GPW = 128/F nodes per wave; 4 waves per block.
    int aggblocks64 = (N + 7) / 8;     // F=64: 2 nodes/wave * 4 waves
    int aggblocks32 = (N + 15) / 16;   // F=32: 4 nodes/wave * 4 waves

    // layer 1: x[N,128] -> bufG h' (fp16) -> bufZ (fp32, relu)
    gemm_scale<128, 64><<<gblocks, 512, 0, stream>>>(x, W1, dinv, bufG, N);
    agg_pull<64, true><<<aggblocks64, 256, 0, stream>>>(bufG, dinv, b1, edge_src, offsets, bufZ, N);
    // layer 2
    gemm_scale<64, 64><<<gblocks, 512, 0, stream>>>(bufZ, W2, dinv, bufG, N);
    agg_pull<64, true><<<aggblocks64, 256, 0, stream>>>(bufG, dinv, b2, edge_src, offsets, bufZ, N);
    // layer 3: 32-wide, write z directly into d_out tail
    gemm_scale<64, 32><<<gblocks, 256, 0, stream>>>(bufZ, W3, dinv, bufG, N);
    agg_pull<32, false><<<aggblocks32, 256, 0, stream>>>(bufG, dinv, b3, edge_src, offsets, zout, N);
    // decode: per-node uv precompute (fp16), then per-edge gather+epilogue
    gemm_uv<<<gblocks, 512, 0, stream>>>(zout, lpW1, uvbuf, N);
    decode_edge<<<(EL + 31) / 32, 256, 0, stream>>>(uvbuf, eli, EL, lpb1, lpW2, lpb2, (float*)d_out);
}

// Round 6
// 457.798 us; speedup vs baseline: 2.7638x; 1.0111x over previous
//
#include <hip/hip_runtime.h>
#include <hip/hip_bf16.h>
#include <hip/hip_fp16.h>

// MusicGNN — 3-layer GCN encoder + MLP link predictor.
// N=100000, F_IN=128, HID=64, OUT=32, E=3.2M edges, EL=1M label edges.
// Inputs: float32 (x, weights, biases), int32 (edge indices).
// Output float32: [link_pred (1M) | z (100000*32)] concatenated flat.
//
// R17: agg_pull lane-widening (validated by R16's decode_edge probe:
// gather kernels are VMEM-issue/latency-bound, not fabric-bound).
// Each lane now owns a 16B float4 slice (8 halfs): F=64 -> 8 lanes/node,
// 8 nodes/wave; F=32 -> 4 lanes/node, 16 nodes/wave. One gather instr
// services one edge of EVERY group (~7x fewer VMEM instrs, same bytes).
// edge_src: one cooperative load + __shfl broadcast within the group
// (DS pipe) replaces 8 broadcast VMEM loads. Two accumulator banks for
// fp32 add ILP. Everything else = R16.

#define BINA_CHUNK 8192

// ---------------- per-chunk bucket histogram ----------------

__global__ __launch_bounds__(512) void bhist_kernel(const int* __restrict__ colv,
                                                    int* __restrict__ chist,
                                                    int E, int nbuk) {
    __shared__ int hist[800];
    int base = blockIdx.x * BINA_CHUNK;
    int end = min(base + BINA_CHUNK, E);
    for (int i = threadIdx.x; i < nbuk; i += 512) hist[i] = 0;
    __syncthreads();
    int e = base + threadIdx.x * 4;
    for (; e + 4 <= end; e += 2048) {
        int4 c4 = *(const int4*)&colv[e];
        atomicAdd(&hist[c4.x >> 7], 1);
        atomicAdd(&hist[c4.y >> 7], 1);
        atomicAdd(&hist[c4.z >> 7], 1);
        atomicAdd(&hist[c4.w >> 7], 1);
    }
    for (; e < end; ++e) atomicAdd(&hist[colv[e] >> 7], 1);
    __syncthreads();
    for (int b = threadIdx.x; b < nbuk; b += 512)
        chist[(size_t)blockIdx.x * nbuk + b] = hist[b];
}

// ---------------- column scan: chist[c][b] -> exclusive prefix over c ----------------

__global__ __launch_bounds__(256) void colscan_kernel(int* __restrict__ chist,
                                                      int* __restrict__ bcount,
                                                      int nchunk, int nbuk) {
    __shared__ int sh[256];
    const int b = blockIdx.x;
    const int c0 = threadIdx.x * 4;
    int v[4]; int s = 0;
#pragma unroll
    for (int i = 0; i < 4; ++i) {
        int c = c0 + i;
        v[i] = (c < nchunk) ? chist[(size_t)c * nbuk + b] : 0;
        s += v[i];
    }
    sh[threadIdx.x] = s;
    __syncthreads();
#pragma unroll
    for (int off = 1; off < 256; off <<= 1) {
        int y = (threadIdx.x >= (unsigned)off) ? sh[threadIdx.x - off] : 0;
        __syncthreads();
        sh[threadIdx.x] += y;
        __syncthreads();
    }
    int ex = sh[threadIdx.x] - s;
#pragma unroll
    for (int i = 0; i < 4; ++i) {
        int c = c0 + i;
        if (c < nchunk) { chist[(size_t)c * nbuk + b] = ex; ex += v[i]; }
    }
    if (threadIdx.x == 255) bcount[b] = sh[255];
}

// ---------------- bucket scan ----------------

__global__ __launch_bounds__(256) void bscan_kernel(const int* __restrict__ bcount,
                                                    int* __restrict__ bbase,
                                                    int nbuk, int* __restrict__ offsets, int N) {
    __shared__ int sh[256];
    int base = threadIdx.x * 4;
    int v[4]; int tsum = 0;
#pragma unroll
    for (int i = 0; i < 4; ++i) { int idx = base + i; v[i] = (idx < nbuk) ? bcount[idx] : 0; tsum += v[i]; }
    sh[threadIdx.x] = tsum;
    __syncthreads();
#pragma unroll
    for (int off = 1; off < 256; off <<= 1) {
        int y = (threadIdx.x >= (unsigned)off) ? sh[threadIdx.x - off] : 0;
        __syncthreads();
        sh[threadIdx.x] += y;
        __syncthreads();
    }
    int ex = sh[threadIdx.x] - tsum;
#pragma unroll
    for (int i = 0; i < 4; ++i) {
        int idx = base + i;
        if (idx < nbuk) { bbase[idx] = ex; ex += v[i]; }
        else if (idx == nbuk) { bbase[idx] = ex; offsets[N] = ex; }  // = E
    }
}

// ---------------- Phase A: scatter into buckets (deterministic chunk bases) ----------------

__global__ __launch_bounds__(512) void binA_kernel(const int* __restrict__ rowv,
                                                   const int* __restrict__ colv,
                                                   const int* __restrict__ chist,
                                                   const int* __restrict__ bbase,
                                                   int* __restrict__ pairs,
                                                   int E, int nbuk) {
    __shared__ int pos[800];
    int base = blockIdx.x * BINA_CHUNK;
    int end = min(base + BINA_CHUNK, E);
    for (int b = threadIdx.x; b < nbuk; b += 512)
        pos[b] = bbase[b] + chist[(size_t)blockIdx.x * nbuk + b];
    __syncthreads();
    int e = base + threadIdx.x * 4;
    for (; e + 4 <= end; e += 2048) {
        int4 c4 = *(const int4*)&colv[e];
        int4 r4 = *(const int4*)&rowv[e];
        int g0 = atomicAdd(&pos[c4.x >> 7], 1); pairs[g0] = (r4.x << 7) | (c4.x & 127);
        int g1 = atomicAdd(&pos[c4.y >> 7], 1); pairs[g1] = (r4.y << 7) | (c4.y & 127);
        int g2 = atomicAdd(&pos[c4.z >> 7], 1); pairs[g2] = (r4.z << 7) | (c4.z & 127);
        int g3 = atomicAdd(&pos[c4.w >> 7], 1); pairs[g3] = (r4.w << 7) | (c4.w & 127);
    }
    for (; e < end; ++e) {
        int c = colv[e];
        int g = atomicAdd(&pos[c >> 7], 1);
        pairs[g] = (rowv[e] << 7) | (c & 127);
    }
}

// ---------------- Phase B: per bucket — node hist, scan, offsets+dinv, scatter ----------------

__global__ __launch_bounds__(512) void binB_kernel(const int* __restrict__ pairs,
                                                   const int* __restrict__ bbase,
                                                   int* __restrict__ offsets,
                                                   float* __restrict__ dinv,
                                                   int* __restrict__ edge_src, int N) {
    __shared__ int lcnt[128];
    __shared__ int sc[128];
    __shared__ int lcur[128];
    int nodeBeg = blockIdx.x << 7;
    int segBeg = bbase[blockIdx.x];
    int segEnd = bbase[blockIdx.x + 1];
    if (threadIdx.x < 128) lcnt[threadIdx.x] = 0;
    __syncthreads();
    for (int e = segBeg + threadIdx.x; e < segEnd; e += 512)
        atomicAdd(&lcnt[pairs[e] & 127], 1);
    __syncthreads();
    int v = (threadIdx.x < 128) ? lcnt[threadIdx.x] : 0;
    if (threadIdx.x < 128) sc[threadIdx.x] = v;
    __syncthreads();
    for (int off = 1; off < 128; off <<= 1) {
        int y = 0;
        if (threadIdx.x < 128 && threadIdx.x >= (unsigned)off) y = sc[threadIdx.x - off];
        __syncthreads();
        if (threadIdx.x < 128) sc[threadIdx.x] += y;
        __syncthreads();
    }
    if (threadIdx.x < 128) {
        int ex = sc[threadIdx.x] - v;
        lcur[threadIdx.x] = ex;
        int node = nodeBeg + threadIdx.x;
        if (node < N) {
            offsets[node] = segBeg + ex;
            dinv[node] = rsqrtf((float)(v + 1));
        }
    }
    __syncthreads();
    for (int e = segBeg + threadIdx.x; e < segEnd; e += 512) {
        int p = pairs[e];
        int rel = atomicAdd(&lcur[p & 127], 1);
        edge_src[segBeg + rel] = p >> 7;
    }
}

// ---------------- GEMM + dinv scale, fp16 out ----------------
// 2 nodes x 4 outs per thread; W staged per K-half; no VGPR caps.

template <int K, int NOUT>
__global__ __launch_bounds__(32 * (NOUT / 4)) void gemm_scale(const float* __restrict__ in_,
                                                              const float* __restrict__ W,
                                                              const float* __restrict__ dinv,
                                                              __half* __restrict__ out, int N) {
    constexpr int TPB = 32 * (NOUT / 4);      // 512 (NOUT=64) / 256 (NOUT=32)
    constexpr int KS = (K > 64) ? 64 : K;     // stage depth
    constexpr int XPITCH = KS + 4;
    __shared__ float xs[64 * XPITCH];
    __shared__ float ws[KS * NOUT];

    const int tid = threadIdx.x;
    const int nodeBase = blockIdx.x * 64;

    const int jg = tid % (NOUT / 4);
    const int ng = tid / (NOUT / 4);          // 0..31, 2 nodes each

    float acc[2][4];
#pragma unroll
    for (int i = 0; i < 2; ++i)
#pragma unroll
        for (int j = 0; j < 4; ++j) acc[i][j] = 0.f;

    for (int kh = 0; kh < K / KS; ++kh) {
        if (kh) __syncthreads();   // previous compute done before overwrite
        for (int i = tid; i < KS * NOUT / 4; i += TPB)
            *(float4*)&ws[i * 4] = *(const float4*)&W[(size_t)kh * KS * NOUT + i * 4];
        for (int i = tid; i < 64 * KS / 4; i += TPB) {
            int row = i / (KS / 4), c = i % (KS / 4);
            int src = nodeBase + row; if (src >= N) src = N - 1;
            *(float4*)&xs[row * XPITCH + c * 4] =
                *(const float4*)&in_[(size_t)src * K + kh * KS + c * 4];
        }
        __syncthreads();

#pragma unroll 4
        for (int kc = 0; kc < KS / 4; ++kc) {
            float4 xv[2], wv[4];
#pragma unroll
            for (int ni = 0; ni < 2; ++ni)
                xv[ni] = *(const float4*)&xs[(ng * 2 + ni) * XPITCH + kc * 4];
#pragma unroll
            for (int t = 0; t < 4; ++t)
                wv[t] = *(const float4*)&ws[(kc * 4 + t) * NOUT + jg * 4];
#pragma unroll
            for (int ni = 0; ni < 2; ++ni) {
                acc[ni][0] = fmaf(xv[ni].x, wv[0].x, acc[ni][0]);
                acc[ni][1] = fmaf(xv[ni].x, wv[0].y, acc[ni][1]);
                acc[ni][2] = fmaf(xv[ni].x, wv[0].z, acc[ni][2]);
                acc[ni][3] = fmaf(xv[ni].x, wv[0].w, acc[ni][3]);
                acc[ni][0] = fmaf(xv[ni].y, wv[1].x, acc[ni][0]);
                acc[ni][1] = fmaf(xv[ni].y, wv[1].y, acc[ni][1]);
                acc[ni][2] = fmaf(xv[ni].y, wv[1].z, acc[ni][2]);
                acc[ni][3] = fmaf(xv[ni].y, wv[1].w, acc[ni][3]);
                acc[ni][0] = fmaf(xv[ni].z, wv[2].x, acc[ni][0]);
                acc[ni][1] = fmaf(xv[ni].z, wv[2].y, acc[ni][1]);
                acc[ni][2] = fmaf(xv[ni].z, wv[2].z, acc[ni][2]);
                acc[ni][3] = fmaf(xv[ni].z, wv[2].w, acc[ni][3]);
                acc[ni][0] = fmaf(xv[ni].w, wv[3].x, acc[ni][0]);
                acc[ni][1] = fmaf(xv[ni].w, wv[3].y, acc[ni][1]);
                acc[ni][2] = fmaf(xv[ni].w, wv[3].z, acc[ni][2]);
                acc[ni][3] = fmaf(xv[ni].w, wv[3].w, acc[ni][3]);
            }
        }
    }

#pragma unroll
    for (int ni = 0; ni < 2; ++ni) {
        int node = nodeBase + ng * 2 + ni;
        if (node < N) {
            float dn = dinv[node];
            __half2* op = (__half2*)(out + (size_t)node * NOUT + jg * 4);
            op[0] = __floats2half2_rn(acc[ni][0] * dn, acc[ni][1] * dn);
            op[1] = __floats2half2_rn(acc[ni][2] * dn, acc[ni][3] * dn);
        }
    }
}

// ---------------- Pull aggregation: float4 (16B) gathers, shfl-broadcast indices ----------------
// LPN = F/8 lanes per node (each lane owns 8 features = 16B); GPW = 64/LPN nodes/wave.
// One gather instruction services one edge of every group. UNROLL = LPN.

template <int F, bool RELU>
__global__ __launch_bounds__(256) void agg_pull(const __half* __restrict__ h,
                                                const float* __restrict__ dinv,
                                                const float* __restrict__ bias,
                                                const int* __restrict__ edge_src,
                                                const int* __restrict__ offsets,
                                                float* __restrict__ out, int N) {
    constexpr int LPN = F / 8;        // lanes per node: F=64 -> 8, F=32 -> 4
    constexpr int GPW = 64 / LPN;     // nodes per wave: 8 / 16
    constexpr int UNR = LPN;          // edges per iteration per node
    int lane = threadIdx.x & 63;
    int wave = (blockIdx.x * 256 + (int)threadIdx.x) >> 6;
    int g = lane / LPN;
    int fl = lane % LPN;              // 16B slice index within row
    int gbase = lane & ~(LPN - 1);    // first lane of my group
    int node = wave * GPW + g;
    if (node >= N) return;
    float dn = dinv[node];
    int beg = offsets[node], end = offsets[node + 1];
    const float4* __restrict__ hp4 = (const float4*)h;   // row stride = LPN float4s

    // self-loop
    float4 sv = hp4[(size_t)node * LPN + fl];
    float2 s0 = __half22float2(*(const __half2*)&sv.x);
    float2 s1 = __half22float2(*(const __half2*)&sv.y);
    float2 s2 = __half22float2(*(const __half2*)&sv.z);
    float2 s3 = __half22float2(*(const __half2*)&sv.w);
    float aA[8] = {s0.x, s0.y, s1.x, s1.y, s2.x, s2.y, s3.x, s3.y};
    float aB[8] = {0.f, 0.f, 0.f, 0.f, 0.f, 0.f, 0.f, 0.f};

    int j = beg;
    for (; j + UNR <= end; j += UNR) {
        int smy = edge_src[j + fl];            // one index per lane
        int sk[UNR];
#pragma unroll
        for (int k = 0; k < UNR; ++k)
            sk[k] = __shfl(smy, gbase + k, 64);
        float4 v[UNR];
#pragma unroll
        for (int k = 0; k < UNR; ++k)
            v[k] = hp4[(size_t)sk[k] * LPN + fl];
#pragma unroll
        for (int k = 0; k < UNR; ++k) {
            float2 p0 = __half22float2(*(const __half2*)&v[k].x);
            float2 p1 = __half22float2(*(const __half2*)&v[k].y);
            float2 p2 = __half22float2(*(const __half2*)&v[k].z);
            float2 p3 = __half22float2(*(const __half2*)&v[k].w);
            float* a = (k & 1) ? aB : aA;
            a[0] += p0.x; a[1] += p0.y; a[2] += p1.x; a[3] += p1.y;
            a[4] += p2.x; a[5] += p2.y; a[6] += p3.x; a[7] += p3.y;
        }
    }
    // tail: r = end - j < UNR
    if (j < end) {
        int r = end - j;
        int smy = (fl < r) ? edge_src[j + fl] : 0;
        for (int k = 0; k < r; ++k) {
            int sk = __shfl(smy, gbase + k, 64);
            float4 v = hp4[(size_t)sk * LPN + fl];
            float2 p0 = __half22float2(*(const __half2*)&v.x);
            float2 p1 = __half22float2(*(const __half2*)&v.y);
            float2 p2 = __half22float2(*(const __half2*)&v.z);
            float2 p3 = __half22float2(*(const __half2*)&v.w);
            float* a = (k & 1) ? aB : aA;
            a[0] += p0.x; a[1] += p0.y; a[2] += p1.x; a[3] += p1.y;
            a[4] += p2.x; a[5] += p2.y; a[6] += p3.x; a[7] += p3.y;
        }
    }

    float4 bva = *(const float4*)&bias[fl * 8];
    float4 bvb = *(const float4*)&bias[fl * 8 + 4];
    float r0 = (aA[0] + aB[0]) * dn + bva.x;
    float r1 = (aA[1] + aB[1]) * dn + bva.y;
    float r2 = (aA[2] + aB[2]) * dn + bva.z;
    float r3 = (aA[3] + aB[3]) * dn + bva.w;
    float r4 = (aA[4] + aB[4]) * dn + bvb.x;
    float r5 = (aA[5] + aB[5]) * dn + bvb.y;
    float r6 = (aA[6] + aB[6]) * dn + bvb.z;
    float r7 = (aA[7] + aB[7]) * dn + bvb.w;
    if (RELU) {
        r0 = fmaxf(r0, 0.f); r1 = fmaxf(r1, 0.f); r2 = fmaxf(r2, 0.f); r3 = fmaxf(r3, 0.f);
        r4 = fmaxf(r4, 0.f); r5 = fmaxf(r5, 0.f); r6 = fmaxf(r6, 0.f); r7 = fmaxf(r7, 0.f);
    }
    float* op = &out[(size_t)node * F + fl * 8];
    *(float4*)op = make_float4(r0, r1, r2, r3);
    *(float4*)(op + 4) = make_float4(r4, r5, r6, r7);
}

// ---------------- Decode stage 1: uv[n] = [z@W1_top | z@W1_bot] (fp16 out) ----------------
// 2 nodes per thread, 512 threads.

__global__ __launch_bounds__(512) void gemm_uv(const float* __restrict__ z,   // [N,32]
                                               const float* __restrict__ W1,  // [64,64]
                                               __half* __restrict__ uv, int N) {
    constexpr int ZPITCH = 36;
    __shared__ float zs[64 * ZPITCH];
    __shared__ float ws[64 * 64];
    const int tid = threadIdx.x;
    const int nodeBase = blockIdx.x * 64;

    for (int i = tid; i < 64 * 64 / 4; i += 512)
        *(float4*)&ws[i * 4] = *(const float4*)&W1[i * 4];
    for (int i = tid; i < 64 * 8; i += 512) {
        int row = i / 8, c = i % 8;
        int src = nodeBase + row; if (src >= N) src = N - 1;
        *(float4*)&zs[row * ZPITCH + c * 4] = *(const float4*)&z[(size_t)src * 32 + c * 4];
    }
    __syncthreads();

    const int jg = tid % 16;
    const int ng = tid / 16;     // 0..31, 2 nodes each

    float au[2][4], av[2][4];
#pragma unroll
    for (int i = 0; i < 2; ++i)
#pragma unroll
        for (int j = 0; j < 4; ++j) { au[i][j] = 0.f; av[i][j] = 0.f; }

#pragma unroll 4
    for (int kc = 0; kc < 8; ++kc) {            // K = 32
        float4 xv[2], wu[4], wv2[4];
#pragma unroll
        for (int ni = 0; ni < 2; ++ni)
            xv[ni] = *(const float4*)&zs[(ng * 2 + ni) * ZPITCH + kc * 4];
#pragma unroll
        for (int t = 0; t < 4; ++t) {
            wu[t]  = *(const float4*)&ws[(kc * 4 + t) * 64 + jg * 4];
            wv2[t] = *(const float4*)&ws[(32 + kc * 4 + t) * 64 + jg * 4];
        }
#pragma unroll
        for (int ni = 0; ni < 2; ++ni) {
            float xk[4] = {xv[ni].x, xv[ni].y, xv[ni].z, xv[ni].w};
#pragma unroll
            for (int t = 0; t < 4; ++t) {
                au[ni][0] = fmaf(xk[t], wu[t].x, au[ni][0]);
                au[ni][1] = fmaf(xk[t], wu[t].y, au[ni][1]);
                au[ni][2] = fmaf(xk[t], wu[t].z, au[ni][2]);
                au[ni][3] = fmaf(xk[t], wu[t].w, au[ni][3]);
                av[ni][0] = fmaf(xk[t], wv2[t].x, av[ni][0]);
                av[ni][1] = fmaf(xk[t], wv2[t].y, av[ni][1]);
                av[ni][2] = fmaf(xk[t], wv2[t].z, av[ni][2]);
                av[ni][3] = fmaf(xk[t], wv2[t].w, av[ni][3]);
            }
        }
    }

#pragma unroll
    for (int ni = 0; ni < 2; ++ni) {
        int node = nodeBase + ng * 2 + ni;
        if (node < N) {
            __half2* pu = (__half2*)(uv + (size_t)node * 128 + jg * 4);
            pu[0] = __floats2half2_rn(au[ni][0], au[ni][1]);
            pu[1] = __floats2half2_rn(au[ni][2], au[ni][3]);
            __half2* pv = (__half2*)(uv + (size_t)node * 128 + 64 + jg * 4);
            pv[0] = __floats2half2_rn(av[ni][0], av[ni][1]);
            pv[1] = __floats2half2_rn(av[ni][2], av[ni][3]);
        }
    }
}

// ---------------- Decode stage 2: link_pred[e] = relu(u[a]+v[b]+b1)·w2 + b2 ----------------
// 8 lanes/edge, float4 (16B) uv loads, 3-deep shuffle reduce.

__global__ __launch_bounds__(256) void decode_edge(const __half* __restrict__ uv,
                                                   const int* __restrict__ eli, int EL,
                                                   const float* __restrict__ lpb1,
                                                   const float* __restrict__ lpW2,
                                                   const float* __restrict__ lpb2,
                                                   float* __restrict__ out) {
    const int sub = threadIdx.x & 7;
    float4 b1a = *(const float4*)&lpb1[sub * 8];
    float4 b1b = *(const float4*)&lpb1[sub * 8 + 4];
    float4 w2a = *(const float4*)&lpW2[sub * 8];
    float4 w2b = *(const float4*)&lpW2[sub * 8 + 4];
    const float b2v = lpb2[0];
    int e = blockIdx.x * 32 + (threadIdx.x >> 3);
    if (e >= EL) return;
    int a = eli[e], b = eli[EL + e];
    float4 ra = *(const float4*)(uv + (size_t)a * 128 + sub * 8);        // 16B: 8 halfs of u[a]
    float4 rb = *(const float4*)(uv + (size_t)b * 128 + 64 + sub * 8);   // 16B: 8 halfs of v[b]
    float2 a01 = __half22float2(*(const __half2*)&ra.x);
    float2 a23 = __half22float2(*(const __half2*)&ra.y);
    float2 a45 = __half22float2(*(const __half2*)&ra.z);
    float2 a67 = __half22float2(*(const __half2*)&ra.w);
    float2 b01 = __half22float2(*(const __half2*)&rb.x);
    float2 b23 = __half22float2(*(const __half2*)&rb.y);
    float2 b45 = __half22float2(*(const __half2*)&rb.z);
    float2 b67 = __half22float2(*(const __half2*)&rb.w);
    float p = fmaxf(a01.x + b01.x + b1a.x, 0.f) * w2a.x;
    p = fmaf(fmaxf(a01.y + b01.y + b1a.y, 0.f), w2a.y, p);
    p = fmaf(fmaxf(a23.x + b23.x + b1a.z, 0.f), w2a.z, p);
    p = fmaf(fmaxf(a23.y + b23.y + b1a.w, 0.f), w2a.w, p);
    p = fmaf(fmaxf(a45.x + b45.x + b1b.x, 0.f), w2b.x, p);
    p = fmaf(fmaxf(a45.y + b45.y + b1b.y, 0.f), w2b.y, p);
    p = fmaf(fmaxf(a67.x + b67.x + b1b.z, 0.f), w2b.z, p);
    p = fmaf(fmaxf(a67.y + b67.y + b1b.w, 0.f), w2b.w, p);
    p += __shfl_down(p, 4, 8);
    p += __shfl_down(p, 2, 8);
    p += __shfl_down(p, 1, 8);
    if (sub == 0) out[e] = p + b2v;
}

// ---------------- launch ----------------

extern "C" void kernel_launch(void* const* d_in, const int* in_sizes, int n_in,
                              void* d_out, int out_size, void* d_ws, size_t ws_size,
                              hipStream_t stream) {
    const float* x    = (const float*)d_in[0];
    const int* ei     = (const int*)d_in[1];
    const int* eli    = (const int*)d_in[2];
    const float* W1   = (const float*)d_in[3];
    const float* b1   = (const float*)d_in[4];
    const float* W2   = (const float*)d_in[5];
    const float* b2   = (const float*)d_in[6];
    const float* W3   = (const float*)d_in[7];
    const float* b3   = (const float*)d_in[8];
    const float* lpW1 = (const float*)d_in[9];
    const float* lpb1 = (const float*)d_in[10];
    const float* lpW2 = (const float*)d_in[11];
    const float* lpb2 = (const float*)d_in[12];

    const int N  = in_sizes[0] / 128;   // 100000
    const int E  = in_sizes[1] / 2;     // 3200000
    const int EL = in_sizes[2] / 2;     // 1000000

    char* p = (char*)d_ws;
    auto alloc = [&](size_t bytes) { void* r = (void*)p; p += (bytes + 255) & ~(size_t)255; return r; };
    float* dinv     = (float*)alloc((size_t)N * 4);
    int*   offsets  = (int*)alloc((size_t)(N + 1) * 4);
    int*   bcount   = (int*)alloc(1024 * 4);
    int*   bbase    = (int*)alloc(1024 * 4);
    int*   edge_src = (int*)alloc((size_t)E * 4);
    __half* bufG    = (__half*)alloc((size_t)N * 64 * 2);   // fp16 messages h'
    float* bufZ     = (float*)alloc((size_t)N * 64 * 4);    // fp32 z1/z2
    __half* uvbuf   = (__half*)alloc((size_t)N * 128 * 2);  // fp16 uv
    int*   pairs    = (int*)uvbuf;  // alias: pairs (12.8MB) dead before gemm_uv writes uv
    int*   chist    = (int*)bufZ;   // alias: chist (1.3MB) dead before agg_pull writes bufZ

    const int* rowv = ei;        // edge_index[0] = source
    const int* colv = ei + E;    // edge_index[1] = target

    int nbuk = (N + 127) / 128;                      // 782
    int nchunk = (E + BINA_CHUNK - 1) / BINA_CHUNK;  // 391 (<=1024 required by colscan)

    bhist_kernel<<<nchunk, 512, 0, stream>>>(colv, chist, E, nbuk);
    colscan_kernel<<<nbuk, 256, 0, stream>>>(chist, bcount, nchunk, nbuk);
    bscan_kernel<<<1, 256, 0, stream>>>(bcount, bbase, nbuk, offsets, N);
    binA_kernel<<<nchunk, 512, 0, stream>>>(rowv, colv, chist, bbase, pairs, E, nbuk);
    binB_kernel<<<nbuk, 512, 0, stream>>>(pairs, bbase, offsets, dinv, edge_src, N);

    float* zout = (float*)d_out + EL;   // z lives in the output tail (float32)

    int gblocks = (N + 63) / 64;  // 1563

    // agg_pull: F=64 -> 8 nodes/wave * 4 waves = 32 nodes/block;
    //           F=32 -> 16 nodes/wave * 4 waves = 64 nodes/block.
    int aggblocks64 = (N + 31) / 32;   // 3125
    int aggblocks32 = (N + 63) / 64;   // 1563

    // layer 1: x[N,128] -> bufG h' (fp16) -> bufZ (fp32, relu)
    gemm_scale<128, 64><<<gblocks, 512, 0, stream>>>(x, W1, dinv, bufG, N);
    agg_pull<64, true><<<aggblocks64, 256, 0, stream>>>(bufG, dinv, b1, edge_src, offsets, bufZ, N);
    // layer 2
    gemm_scale<64, 64><<<gblocks, 512, 0, stream>>>(bufZ, W2, dinv, bufG, N);
    agg_pull<64, true><<<aggblocks64, 256, 0, stream>>>(bufG, dinv, b2, edge_src, offsets, bufZ, N);
    // layer 3: 32-wide, write z directly into d_out tail
    gemm_scale<64, 32><<<gblocks, 256, 0, stream>>>(bufZ, W3, dinv, bufG, N);
    agg_pull<32, false><<<aggblocks32, 256, 0, stream>>>(bufG, dinv, b3, edge_src, offsets, zout, N);
    // decode: per-node uv precompute (fp16), then per-edge gather+epilogue
    gemm_uv<<<gblocks, 512, 0, stream>>>(zout, lpW1, uvbuf, N);
    decode_edge<<<(EL + 31) / 32, 256, 0, stream>>>(uvbuf, eli, EL, lpb1, lpW2, lpb2, (float*)d_out);
}